// Round 7
// baseline (189.320 us; speedup 1.0000x reference)
//
#include <hip/hip_runtime.h>
#include <math.h>

#define HH 128
#define BB 2
#define NN 48
#define TT 24
#define MM 192
#define LL 20
#define NT (BB*NN*TT)   /* 2304 */
#define RSQRT_H 0.08838834764831845f  /* 1/sqrt(128) */
#define RADIUS_C 30.0f

struct P {
    const float *astate, *amask, *polylines, *poly_mask;
    const int *ptype, *tlst, *route;
    const float *ae_w0,*ae_b0,*ae_w1,*ae_b1,*ae_w2,*ae_b2;
    const float *mp_w0,*mp_b0,*mp_w1,*mp_b1;
    const float *type_emb,*tl_emb,*route_emb;
    const float *mo_w0,*mo_b0,*mo_w1,*mo_b1;
    const float *mr_w0,*mr_b0,*mr_w1,*mr_b1;
    const float *nr_w0,*nr_b0,*nr_w1,*nr_b1;
    const float *to_w0,*to_b0,*to_w1,*to_b1;
    float *tau,*map_ctx,*nbr_ctx;
    float *a_emb,*map_node,*map_nodeT,*map_center;
};

// keep a load alive without using its value (prevents DCE; warms L2/L3)
__device__ __forceinline__ void keep4(float4 v) {
    asm volatile("" :: "v"(v.x), "v"(v.y), "v"(v.z), "v"(v.w));
}

// ---- per-phase LDS layouts (float4 members for conflict-free b128 access) ----
struct SME { float pts[LL*2]; float h1[LL][HH]; float mx[2][HH]; float hb[HH]; float pr[2][HH]; float hb2[HH]; };
struct SAG { float xin[4][5]; float h1[4][HH]; float h2[4][HH]; float p1[2][4][HH]; };
struct SMA { float mnL[16][MM]; float4 w4L[HH]; float w1L[HH]; float4 aq4L[HH]; float lg[4][MM]; float4 p4L[MM]; float invL[4]; float pc[2][4][HH]; };
struct SNB { float aVL[NN][129]; float pjL[NN][8]; float4 wAL[HH]; float4 wBL[HH]; float aqL[HH][8]; float sPL[4][6][NN]; float dPL[4][6][NN]; float lgL[6][NN]; float pL[NN][8]; float pcL[2][6][HH]; };
struct STA2 { float xinT[3*HH][2]; float p1L[2][2][HH]; float h1T[HH][2]; };

// ---------------- 1a: map polyline encoder (one bm per block, 256 thr) ----------------
__device__ void do_map_enc(const P& p, SME& s, int bm) {
    int tid = threadIdx.x, pp = tid >> 7, c = tid & 127;
    if (tid < LL*2) s.pts[tid] = p.polylines[(size_t)bm*LL*2 + tid];
    __syncthreads();
    {
        float w0x = p.mp_w0[c], w0y = p.mp_w0[HH + c], b0 = p.mp_b0[c];
        #pragma unroll
        for (int i = 0; i < 10; ++i) {
            int pt_ = pp + 2*i;
            s.h1[pt_][c] = fmaxf(fmaf(s.pts[2*pt_], w0x, fmaf(s.pts[2*pt_+1], w0y, b0)), 0.f);
        }
    }
    if (tid < 2) {
        float sum = 0.f;
        for (int q = 0; q < LL; ++q) sum += s.pts[2*q + tid];
        p.map_center[bm*2 + tid] = sum * (1.0f / LL);
    }
    __syncthreads();
    {
        float acc[10];
        float b1 = p.mp_b1[c];
        #pragma unroll
        for (int i = 0; i < 10; ++i) acc[i] = b1;
        for (int k = 0; k < HH; ++k) {
            float wv = p.mp_w1[k*HH + c];
            #pragma unroll
            for (int i = 0; i < 10; ++i) acc[i] = fmaf(s.h1[pp + 2*i][k], wv, acc[i]);
        }
        float m10 = acc[0];
        #pragma unroll
        for (int i = 1; i < 10; ++i) m10 = fmaxf(m10, acc[i]);
        s.mx[pp][c] = m10;
    }
    __syncthreads();
    if (tid < HH) {
        float hm = fmaxf(fmaxf(s.mx[0][c], s.mx[1][c]), 0.f);
        int pt = p.ptype[bm]; pt = pt < 0 ? 0 : (pt > 3 ? 3 : pt);
        int tv = p.tlst[bm];  tv = tv < 0 ? 0 : (tv > 7 ? 7 : tv);
        int rv = p.route[bm]; rv = rv < 0 ? 0 : (rv > 1 ? 1 : rv);
        hm += p.type_emb[pt*HH + c] + p.tl_emb[tv*HH + c] + p.route_emb[rv*HH + c];
        s.hb[c] = hm;
    }
    __syncthreads();
    {
        float sum = 0.f;
        int k0 = pp*64;
        for (int k = k0; k < k0 + 64; ++k) sum = fmaf(s.hb[k], p.mo_w0[k*HH + c], sum);
        s.pr[pp][c] = sum;
    }
    __syncthreads();
    if (tid < HH) s.hb2[c] = fmaxf(s.pr[0][c] + s.pr[1][c] + p.mo_b0[c], 0.f);
    __syncthreads();
    {
        float sum = 0.f;
        int k0 = pp*64;
        for (int k = k0; k < k0 + 64; ++k) sum = fmaf(s.hb2[k], p.mo_w1[k*HH + c], sum);
        s.pr[pp][c] = sum;
    }
    __syncthreads();
    if (tid < HH) {
        float a3 = s.pr[0][c] + s.pr[1][c] + p.mo_b1[c];
        float mk = (p.poly_mask[bm] > 0.5f) ? 1.f : 0.f;
        float v = a3 * mk;
        p.map_node[(size_t)bm*HH + c] = v;
        int b = bm / MM, m = bm % MM;
        p.map_nodeT[((size_t)b*HH + c)*MM + m] = v;
    }
}

// ---------------- 1b: agent encoder (4 rows per block, 256 thr) ----------------
__device__ void do_agent_enc(const P& p, SAG& s, int r0) {
    int tid = threadIdx.x, h = tid >> 7, c = tid & 127;
    if (tid < 20) s.xin[tid/5][tid%5] = p.astate[(size_t)r0*5 + tid];
    __syncthreads();
    if (h == 0) {
        float b = p.ae_b0[c];
        float w[5];
        #pragma unroll
        for (int i = 0; i < 5; ++i) w[i] = p.ae_w0[i*HH + c];
        #pragma unroll
        for (int r = 0; r < 4; ++r) {
            float v = b;
            #pragma unroll
            for (int i = 0; i < 5; ++i) v = fmaf(s.xin[r][i], w[i], v);
            s.h1[r][c] = fmaxf(v, 0.f);
        }
    }
    __syncthreads();
    {
        float acc[4] = {0.f,0.f,0.f,0.f};
        int k0 = h*64;
        for (int k = k0; k < k0 + 64; ++k) {
            float wv = p.ae_w1[k*HH + c];
            #pragma unroll
            for (int r = 0; r < 4; ++r) acc[r] = fmaf(s.h1[r][k], wv, acc[r]);
        }
        #pragma unroll
        for (int r = 0; r < 4; ++r) s.p1[h][r][c] = acc[r];
    }
    __syncthreads();
    {
        #pragma unroll
        for (int rr = 0; rr < 2; ++rr) {
            int r = h*2 + rr;
            s.h2[r][c] = fmaxf(s.p1[0][r][c] + s.p1[1][r][c] + p.ae_b1[c], 0.f);
        }
    }
    __syncthreads();
    {
        float acc[4] = {0.f,0.f,0.f,0.f};
        int k0 = h*64;
        for (int k = k0; k < k0 + 64; ++k) {
            float wv = p.ae_w2[k*HH + c];
            #pragma unroll
            for (int r = 0; r < 4; ++r) acc[r] = fmaf(s.h2[r][k], wv, acc[r]);
        }
        #pragma unroll
        for (int r = 0; r < 4; ++r) s.p1[h][r][c] = acc[r];
    }
    __syncthreads();
    {
        #pragma unroll
        for (int rr = 0; rr < 2; ++rr) {
            int r = h*2 + rr;
            int row = r0 + r;
            p.a_emb[(size_t)row*HH + c] = (s.p1[0][r][c] + s.p1[1][r][c] + p.ae_b2[c]) * p.amask[row];
        }
    }
}

// ---------------- 2a: map cross-attention (4 rows per block, 256 thr) ----------------
__device__ void do_map_attn(const P& p, SMA& s, int bnt0) {
    int b   = bnt0 / (NN*TT);
    int tid = threadIdx.x;

    if (tid < HH) {
        int k = tid;
        s.w4L[k] = make_float4(p.mr_w0[k], p.mr_w0[HH+k], p.mr_w0[2*HH+k], p.mr_b0[k]);
        s.w1L[k] = p.mr_w1[k];
    }
    for (int idx = tid; idx < 4*HH; idx += 256) {
        int r = idx >> 7, k = idx & 127;
        ((float*)&s.aq4L[k])[r] = p.a_emb[(size_t)(bnt0 + r)*HH + k];
    }

    float rx[4], ry[4], rd[4];
    if (tid < MM) {
        float mcx = p.map_center[(b*MM + tid)*2];
        float mcy = p.map_center[(b*MM + tid)*2 + 1];
        #pragma unroll
        for (int r = 0; r < 4; ++r) {
            float px = p.astate[(size_t)(bnt0 + r)*5];
            float py = p.astate[(size_t)(bnt0 + r)*5 + 1];
            rx[r] = mcx - px; ry[r] = mcy - py;
            rd[r] = sqrtf(rx[r]*rx[r] + ry[r]*ry[r]);
        }
    }

    const float* mnT = p.map_nodeT + (size_t)b*HH*MM;
    float4 st[3];
    #pragma unroll
    for (int i = 0; i < 3; ++i) {
        int q = tid + 256*i;
        int kk = q / 48, mq = q % 48;
        st[i] = *(const float4*)(mnT + (size_t)kk*MM + mq*4);
    }
    float sacc[4] = {0.f,0.f,0.f,0.f};
    float dt[4]   = {0.f,0.f,0.f,0.f};
    for (int ch = 0; ch < 8; ++ch) {
        __syncthreads();
        #pragma unroll
        for (int i = 0; i < 3; ++i) {
            int q = tid + 256*i;
            int kk = q / 48, mq = q % 48;
            *(float4*)&s.mnL[kk][mq*4] = st[i];
        }
        __syncthreads();
        if (ch < 7) {
            #pragma unroll
            for (int i = 0; i < 3; ++i) {
                int q = tid + 256*i;
                int kk = q / 48, mq = q % 48;
                st[i] = *(const float4*)(mnT + (size_t)(ch+1)*16*MM + (size_t)kk*MM + mq*4);
            }
        }
        if (tid < MM) {
            int k0 = ch*16;
            #pragma unroll
            for (int kk = 0; kk < 16; ++kk) {
                int k = k0 + kk;
                float4 w  = s.w4L[k];
                float  w1 = s.w1L[k];
                float4 aq = s.aq4L[k];
                float  mn = s.mnL[kk][tid];
                #pragma unroll
                for (int r = 0; r < 4; ++r) {
                    float hv = fmaf(rx[r], w.x, fmaf(ry[r], w.y, fmaf(rd[r], w.z, w.w)));
                    sacc[r] = fmaf(fmaxf(hv, 0.f), w1, sacc[r]);
                }
                dt[0] = fmaf(aq.x, mn, dt[0]);
                dt[1] = fmaf(aq.y, mn, dt[1]);
                dt[2] = fmaf(aq.z, mn, dt[2]);
                dt[3] = fmaf(aq.w, mn, dt[3]);
            }
        }
    }

    if (tid < MM) {
        float pm = p.poly_mask[b*MM + tid];
        float b1 = p.mr_b1[0];
        #pragma unroll
        for (int r = 0; r < 4; ++r) {
            float lgt = fmaf(dt[r], RSQRT_H, sacc[r] + b1);
            s.lg[r][tid] = (pm > 0.5f) ? lgt : -1e9f;
        }
    }
    __syncthreads();

    {
        int r = tid >> 6, l = tid & 63;
        float v = fmaxf(fmaxf(s.lg[r][l], s.lg[r][l+64]), s.lg[r][l+128]);
        #pragma unroll
        for (int o = 32; o > 0; o >>= 1) v = fmaxf(v, __shfl_xor(v, o));
        float e0 = expf(s.lg[r][l] - v);
        float e1 = expf(s.lg[r][l+64] - v);
        float e2 = expf(s.lg[r][l+128] - v);
        s.lg[r][l] = e0; s.lg[r][l+64] = e1; s.lg[r][l+128] = e2;
        float sm = e0 + e1 + e2;
        #pragma unroll
        for (int o = 32; o > 0; o >>= 1) sm += __shfl_xor(sm, o);
        if (l == 0) s.invL[r] = 1.0f / sm;
    }
    __syncthreads();
    if (tid < MM) {
        s.p4L[tid] = make_float4(s.lg[0][tid]*s.invL[0], s.lg[1][tid]*s.invL[1],
                                 s.lg[2][tid]*s.invL[2], s.lg[3][tid]*s.invL[3]);
    }
    __syncthreads();

    {
        int half = tid >> 7, c = tid & 127;
        float a0=0.f, a1=0.f, a2=0.f, a3=0.f;
        const float* mnb = p.map_node + ((size_t)b*MM + half*96)*HH + c;
        for (int m = 0; m < 96; ++m) {
            float mv = mnb[(size_t)m*HH];
            float4 pp4 = s.p4L[half*96 + m];
            a0 = fmaf(pp4.x, mv, a0); a1 = fmaf(pp4.y, mv, a1);
            a2 = fmaf(pp4.z, mv, a2); a3 = fmaf(pp4.w, mv, a3);
        }
        s.pc[half][0][c]=a0; s.pc[half][1][c]=a1; s.pc[half][2][c]=a2; s.pc[half][3][c]=a3;
    }
    __syncthreads();
    for (int idx = tid; idx < 4*HH; idx += 256) {
        int r = idx >> 7, c = idx & 127;
        p.map_ctx[(size_t)(bnt0 + r)*HH + c] = s.pc[0][r][c] + s.pc[1][r][c];
    }
}

// ---------------- 2b: neighbor attention (6 n-rows per block, 256 thr) ----------------
__device__ void do_nbr_attn(const P& p, SNB& s, int task) {
    int b   = task / (TT*8);
    int rem = task % (TT*8);
    int t   = rem / 8;
    int n0  = (rem % 8) * 6;
    int tid = threadIdx.x;

    if (tid < NN) {
        int rj = (b*NN + tid)*TT + t;
        s.pjL[tid][0] = p.astate[(size_t)rj*5];
        s.pjL[tid][1] = p.astate[(size_t)rj*5 + 1];
        s.pjL[tid][2] = p.astate[(size_t)rj*5 + 3];
        s.pjL[tid][3] = p.astate[(size_t)rj*5 + 4];
        s.pjL[tid][4] = p.amask[rj];
    }
    if (tid < HH) {
        int k = tid;
        s.wAL[k] = make_float4(p.nr_w0[k], p.nr_w0[HH+k], p.nr_w0[2*HH+k], p.nr_w0[3*HH+k]);
        s.wBL[k] = make_float4(p.nr_w0[4*HH+k], p.nr_b0[k], p.nr_w1[k], 0.f);
    }
    #pragma unroll
    for (int i = 0; i < 6; ++i) {
        int q = tid + 256*i;
        int j = q >> 5, cq = q & 31;
        float4 v = *(const float4*)(p.a_emb + ((size_t)(b*NN + j)*TT + t)*HH + cq*4);
        s.aVL[j][cq*4+0] = v.x; s.aVL[j][cq*4+1] = v.y;
        s.aVL[j][cq*4+2] = v.z; s.aVL[j][cq*4+3] = v.w;
    }
    __syncthreads();
    for (int idx = tid; idx < 6*HH; idx += 256) {
        int r = idx >> 7, k = idx & 127;
        s.aqL[k][r] = s.aVL[n0 + r][k];
    }
    __syncthreads();

    {
        int j  = tid % 48;
        int kg = tid / 48;
        if (kg < 4) {
            float jx = s.pjL[j][0], jy = s.pjL[j][1], jvx = s.pjL[j][2], jvy = s.pjL[j][3];
            float dx[6], dy[6], dvx[6], dvy[6], dd[6];
            #pragma unroll
            for (int r = 0; r < 6; ++r) {
                dx[r]  = s.pjL[n0+r][0] - jx;  dy[r]  = s.pjL[n0+r][1] - jy;
                dvx[r] = s.pjL[n0+r][2] - jvx; dvy[r] = s.pjL[n0+r][3] - jvy;
                dd[r]  = sqrtf(dx[r]*dx[r] + dy[r]*dy[r]);
            }
            float sr[6]  = {0,0,0,0,0,0};
            float dt[6] = {0,0,0,0,0,0};
            int k0 = kg*32;
            for (int kk = 0; kk < 32; ++kk) {
                int k = k0 + kk;
                float4 wa = s.wAL[k], wb = s.wBL[k];
                float4 aA = *(const float4*)&s.aqL[k][0];
                float4 aB = *(const float4*)&s.aqL[k][4];
                float  av = s.aVL[j][k];
                #pragma unroll
                for (int r = 0; r < 6; ++r) {
                    float hv = fmaf(dx[r], wa.x, fmaf(dy[r], wa.y,
                               fmaf(dvx[r], wa.z, fmaf(dvy[r], wa.w,
                               fmaf(dd[r], wb.x, wb.y)))));
                    sr[r] = fmaf(fmaxf(hv, 0.f), wb.z, sr[r]);
                }
                dt[0] = fmaf(aA.x, av, dt[0]); dt[1] = fmaf(aA.y, av, dt[1]);
                dt[2] = fmaf(aA.z, av, dt[2]); dt[3] = fmaf(aA.w, av, dt[3]);
                dt[4] = fmaf(aB.x, av, dt[4]); dt[5] = fmaf(aB.y, av, dt[5]);
            }
            #pragma unroll
            for (int r = 0; r < 6; ++r) { s.sPL[kg][r][j] = sr[r]; s.dPL[kg][r][j] = dt[r]; }
        }
    }
    __syncthreads();

    float b1 = p.nr_b1[0];
    for (int idx = tid; idx < 6*NN; idx += 256) {
        int r = idx / NN, jj = idx % NN;
        int ni = n0 + r;
        float ss  = s.sPL[0][r][jj] + s.sPL[1][r][jj] + s.sPL[2][r][jj] + s.sPL[3][r][jj] + b1;
        float do2 = s.dPL[0][r][jj] + s.dPL[1][r][jj] + s.dPL[2][r][jj] + s.dPL[3][r][jj];
        float ddx = s.pjL[ni][0] - s.pjL[jj][0];
        float ddy = s.pjL[ni][1] - s.pjL[jj][1];
        float dist = sqrtf(ddx*ddx + ddy*ddy);
        bool ok = (s.pjL[ni][4] > 0.5f) && (s.pjL[jj][4] > 0.5f) &&
                  (dist <= RADIUS_C) && (jj != ni);
        s.lgL[r][jj] = ok ? fmaf(do2, RSQRT_H, ss) : -1e9f;
    }
    __syncthreads();

    {
        int wv = tid >> 6, l = tid & 63;
        for (int r = wv; r < 6; r += 4) {
            float v = (l < NN) ? s.lgL[r][l] : -3.4e38f;
            #pragma unroll
            for (int o = 32; o > 0; o >>= 1) v = fmaxf(v, __shfl_xor(v, o));
            float e = (l < NN) ? expf(s.lgL[r][l] - v) : 0.f;
            float sm = e;
            #pragma unroll
            for (int o = 32; o > 0; o >>= 1) sm += __shfl_xor(sm, o);
            if (l < NN) s.lgL[r][l] = e / sm;
        }
    }
    __syncthreads();
    if (tid < NN) {
        #pragma unroll
        for (int r = 0; r < 6; ++r) s.pL[tid][r] = s.lgL[r][tid];
        s.pL[tid][6] = 0.f; s.pL[tid][7] = 0.f;
    }
    __syncthreads();

    {
        int half = tid >> 7, c = tid & 127;
        float acc[6] = {0,0,0,0,0,0};
        for (int jj = half*24; jj < half*24 + 24; ++jj) {
            float av = s.aVL[jj][c];
            float4 pA = *(const float4*)&s.pL[jj][0];
            float4 pB = *(const float4*)&s.pL[jj][4];
            acc[0] = fmaf(pA.x, av, acc[0]); acc[1] = fmaf(pA.y, av, acc[1]);
            acc[2] = fmaf(pA.z, av, acc[2]); acc[3] = fmaf(pA.w, av, acc[3]);
            acc[4] = fmaf(pB.x, av, acc[4]); acc[5] = fmaf(pB.y, av, acc[5]);
        }
        #pragma unroll
        for (int r = 0; r < 6; ++r) s.pcL[half][r][c] = acc[r];
    }
    __syncthreads();
    for (int idx = tid; idx < 6*HH; idx += 256) {
        int r = idx >> 7, c = idx & 127;
        int row = (b*NN + n0 + r)*TT + t;
        p.nbr_ctx[(size_t)row*HH + c] = s.pcL[0][r][c] + s.pcL[1][r][c];
    }
}

// ---------------- kernel A: encoders (960 blocks) ----------------
__global__ __launch_bounds__(256) void k_enc(P p) {
    // L2/L3 warm prefetch: slice the 5 hot 64KB weight matrices across blocks.
    {
        int sgl = (blockIdx.x % 80) * 256 + threadIdx.x;   // [0, 20480)
        int mi  = sgl >> 12;                                // which matrix (4096 f4 each)
        int off = (sgl & 4095) << 2;                        // float offset
        const float* base = p.mp_w1;
        if (mi == 1) base = p.mo_w0;
        else if (mi == 2) base = p.mo_w1;
        else if (mi == 3) base = p.ae_w1;
        else if (mi == 4) base = p.ae_w2;
        keep4(*(const float4*)(base + off));
    }
    __shared__ __align__(16) char smraw[(sizeof(SME) > sizeof(SAG)) ? sizeof(SME) : sizeof(SAG)];
    int task = blockIdx.x;
    if (task < BB*MM) do_map_enc(p, *(SME*)smraw, task);
    else              do_agent_enc(p, *(SAG*)smraw, (task - BB*MM)*4);
}

// ---------------- kernel B: attentions (960 blocks) ----------------
__global__ __launch_bounds__(256) void k_attn(P p) {
    // warm a_emb (73728 f4) + map_node (12288) + map_nodeT (12288) = 98304 f4
    {
        int g = blockIdx.x * 256 + threadIdx.x;
        if (g < 98304) {
            const float* base; int off;
            if (g < 73728)      { base = p.a_emb;     off = g * 4; }
            else if (g < 86016) { base = p.map_node;  off = (g - 73728) * 4; }
            else                { base = p.map_nodeT; off = (g - 86016) * 4; }
            keep4(*(const float4*)(base + off));
        }
    }
    __shared__ __align__(16) char smraw[(sizeof(SMA) > sizeof(SNB)) ? sizeof(SMA) : sizeof(SNB)];
    int task = blockIdx.x;
    if (task < NT/4) do_map_attn(p, *(SMA*)smraw, task*4);
    else             do_nbr_attn(p, *(SNB*)smraw, task - NT/4);
}

// ---------------- kernel C: output MLP (1152 blocks, 2 rows each) ----------------
__global__ __launch_bounds__(256) void k_tau(P p) {
    // warm to_w0 (12288 f4) + to_w1 (2048 f4)
    {
        int g = blockIdx.x * 256 + threadIdx.x;
        if (g < 14336) {
            const float* base; int off;
            if (g < 12288) { base = p.to_w0; off = g * 4; }
            else           { base = p.to_w1; off = (g - 12288) * 4; }
            keep4(*(const float4*)(base + off));
        }
    }
    __shared__ __align__(16) STA2 s;
    int r0  = blockIdx.x * 2;
    int tid = threadIdx.x;

    if (tid < 192) {
        int r = tid / 96, kq = tid % 96;
        const float* src; int co;
        if (kq < 32)      { src = p.a_emb;   co = kq; }
        else if (kq < 64) { src = p.map_ctx; co = kq - 32; }
        else              { src = p.nbr_ctx; co = kq - 64; }
        float4 v = *(const float4*)(src + (size_t)(r0 + r)*HH + co*4);
        int kb = (kq < 32 ? 0 : (kq < 64 ? HH : 2*HH)) + co*4;
        s.xinT[kb+0][r] = v.x; s.xinT[kb+1][r] = v.y;
        s.xinT[kb+2][r] = v.z; s.xinT[kb+3][r] = v.w;
    }
    __syncthreads();
    {
        int c = tid & 127, h = tid >> 7;
        float a0 = 0.f, a1 = 0.f;
        for (int k = h*192; k < h*192 + 192; ++k) {
            float wv = p.to_w0[k*HH + c];
            float2 x = *(const float2*)&s.xinT[k][0];
            a0 = fmaf(x.x, wv, a0);
            a1 = fmaf(x.y, wv, a1);
        }
        s.p1L[h][0][c] = a0;
        s.p1L[h][1][c] = a1;
    }
    __syncthreads();
    {
        int r = tid >> 7, k = tid & 127;
        s.h1T[k][r] = fmaxf(s.p1L[0][r][k] + s.p1L[1][r][k] + p.to_b0[k], 0.f);
    }
    __syncthreads();
    {
        int kh = tid >> 7, rc = tid & 127;
        int r = rc >> 6, c2 = rc & 63;
        float acc = 0.f;
        for (int k = kh*64; k < kh*64 + 64; ++k)
            acc = fmaf(s.h1T[k][r], p.to_w1[k*64 + c2], acc);
        s.p1L[kh][r][c2] = acc;
    }
    __syncthreads();
    if (tid < 128) {
        int r = tid >> 6, c2 = tid & 63;
        float v = (s.p1L[0][r][c2] + s.p1L[1][r][c2] + p.to_b1[c2]) * p.amask[r0 + r];
        p.tau[(size_t)(r0 + r)*64 + c2] = v;
    }
}

extern "C" void kernel_launch(void* const* d_in, const int* in_sizes, int n_in,
                              void* d_out, int out_size, void* d_ws, size_t ws_size,
                              hipStream_t stream)
{
    P p;
    p.astate    = (const float*)d_in[0];
    p.amask     = (const float*)d_in[1];
    p.polylines = (const float*)d_in[2];
    p.poly_mask = (const float*)d_in[3];
    p.ptype     = (const int*)d_in[4];
    p.tlst      = (const int*)d_in[5];
    p.route     = (const int*)d_in[6];
    p.ae_w0 = (const float*)d_in[7];  p.ae_b0 = (const float*)d_in[8];
    p.ae_w1 = (const float*)d_in[9];  p.ae_b1 = (const float*)d_in[10];
    p.ae_w2 = (const float*)d_in[11]; p.ae_b2 = (const float*)d_in[12];
    p.mp_w0 = (const float*)d_in[13]; p.mp_b0 = (const float*)d_in[14];
    p.mp_w1 = (const float*)d_in[15]; p.mp_b1 = (const float*)d_in[16];
    p.type_emb  = (const float*)d_in[17];
    p.tl_emb    = (const float*)d_in[18];
    p.route_emb = (const float*)d_in[19];
    p.mo_w0 = (const float*)d_in[20]; p.mo_b0 = (const float*)d_in[21];
    p.mo_w1 = (const float*)d_in[22]; p.mo_b1 = (const float*)d_in[23];
    p.mr_w0 = (const float*)d_in[24]; p.mr_b0 = (const float*)d_in[25];
    p.mr_w1 = (const float*)d_in[26]; p.mr_b1 = (const float*)d_in[27];
    p.nr_w0 = (const float*)d_in[28]; p.nr_b0 = (const float*)d_in[29];
    p.nr_w1 = (const float*)d_in[30]; p.nr_b1 = (const float*)d_in[31];
    p.to_w0 = (const float*)d_in[32]; p.to_b0 = (const float*)d_in[33];
    p.to_w1 = (const float*)d_in[34]; p.to_b1 = (const float*)d_in[35];

    p.tau     = (float*)d_out;
    p.map_ctx = (float*)d_out + (size_t)NT*64;
    p.nbr_ctx = p.map_ctx + (size_t)NT*HH;

    float* ws    = (float*)d_ws;
    p.a_emb      = ws;                                   // NT*HH
    p.map_node   = p.a_emb + (size_t)NT*HH;              // B*M*HH
    p.map_nodeT  = p.map_node + (size_t)BB*MM*HH;        // B*HH*MM
    p.map_center = p.map_nodeT + (size_t)BB*MM*HH;       // B*M*2

    k_enc <<<BB*MM + NT/4,   256, 0, stream>>>(p);   // 384 + 576 = 960
    k_attn<<<NT/4 + BB*TT*8, 256, 0, stream>>>(p);   // 576 + 384 = 960
    k_tau <<<NT/2,           256, 0, stream>>>(p);   // 1152
}

// Round 8
// 187.864 us; speedup vs baseline: 1.0077x; 1.0077x over previous
//
#include <hip/hip_runtime.h>
#include <math.h>

#define HH 128
#define BB 2
#define NN 48
#define TT 24
#define MM 192
#define LL 20
#define NT (BB*NN*TT)   /* 2304 */
#define RSQRT_H 0.08838834764831845f  /* 1/sqrt(128) */
#define RADIUS_C 30.0f

struct P {
    const float *astate, *amask, *polylines, *poly_mask;
    const int *ptype, *tlst, *route;
    const float *ae_w0,*ae_b0,*ae_w1,*ae_b1,*ae_w2,*ae_b2;
    const float *mp_w0,*mp_b0,*mp_w1,*mp_b1;
    const float *type_emb,*tl_emb,*route_emb;
    const float *mo_w0,*mo_b0,*mo_w1,*mo_b1;
    const float *mr_w0,*mr_b0,*mr_w1,*mr_b1;
    const float *nr_w0,*nr_b0,*nr_w1,*nr_b1;
    const float *to_w0,*to_b0,*to_w1,*to_b1;
    float *tau,*map_ctx,*nbr_ctx;
    float *a_emb,*map_node,*map_nodeT,*map_center;
};

// ---- k_enc LDS layouts ----
struct SME { float pts[LL*2]; float h1[LL][HH]; float mx[2][HH]; float hb[HH]; float pr[2][HH]; float hb2[HH]; };
struct SAG { float xin[4][5]; float h1[4][HH]; float h2[4][HH]; float p1[2][4][HH]; };

// ---- fused attn+tau LDS: phases sequential, big parts unioned (~31 KB) ----
struct SF {
    float4 aq4L[HH];        // query rows r=0..3 in components (persistent)
    float  mctx[4][HH];     // map ctx result
    float  nctx[4][HH];     // nbr ctx result
    float  pc[2][4][HH];    // partial ctx accum / tau p1 (reused each phase)
    union {
        struct {            // map-attention phase
            float  mnL[16][MM];
            float4 w4L[HH];
            float  w1L[HH];
            float  lg[4][MM];
            float4 p4L[MM];
            float  invL[4];
        } m;
        struct {            // nbr-attention phase
            float  pjL[NN][8];
            float4 wAL[HH];
            float4 wBL[HH];
            float  sPL[4][4][NN];
            float  dPL[4][4][NN];
            float  lgN[4][NN];
            float4 pN[NN];
        } n;
        struct {            // tau phase
            float  xinT[3*HH][4];
            float  h1T[HH][4];
        } t;
    } u;
};

// ---------------- 1a: map polyline encoder (one bm per block, 256 thr) ----------------
__device__ void do_map_enc(const P& p, SME& s, int bm) {
    int tid = threadIdx.x, pp = tid >> 7, c = tid & 127;
    if (tid < LL*2) s.pts[tid] = p.polylines[(size_t)bm*LL*2 + tid];
    __syncthreads();
    {
        float w0x = p.mp_w0[c], w0y = p.mp_w0[HH + c], b0 = p.mp_b0[c];
        #pragma unroll
        for (int i = 0; i < 10; ++i) {
            int pt_ = pp + 2*i;
            s.h1[pt_][c] = fmaxf(fmaf(s.pts[2*pt_], w0x, fmaf(s.pts[2*pt_+1], w0y, b0)), 0.f);
        }
    }
    if (tid < 2) {
        float sum = 0.f;
        for (int q = 0; q < LL; ++q) sum += s.pts[2*q + tid];
        p.map_center[bm*2 + tid] = sum * (1.0f / LL);
    }
    __syncthreads();
    {
        float acc[10];
        float b1 = p.mp_b1[c];
        #pragma unroll
        for (int i = 0; i < 10; ++i) acc[i] = b1;
        for (int k = 0; k < HH; ++k) {
            float wv = p.mp_w1[k*HH + c];
            #pragma unroll
            for (int i = 0; i < 10; ++i) acc[i] = fmaf(s.h1[pp + 2*i][k], wv, acc[i]);
        }
        float m10 = acc[0];
        #pragma unroll
        for (int i = 1; i < 10; ++i) m10 = fmaxf(m10, acc[i]);
        s.mx[pp][c] = m10;
    }
    __syncthreads();
    if (tid < HH) {
        float hm = fmaxf(fmaxf(s.mx[0][c], s.mx[1][c]), 0.f);
        int pt = p.ptype[bm]; pt = pt < 0 ? 0 : (pt > 3 ? 3 : pt);
        int tv = p.tlst[bm];  tv = tv < 0 ? 0 : (tv > 7 ? 7 : tv);
        int rv = p.route[bm]; rv = rv < 0 ? 0 : (rv > 1 ? 1 : rv);
        hm += p.type_emb[pt*HH + c] + p.tl_emb[tv*HH + c] + p.route_emb[rv*HH + c];
        s.hb[c] = hm;
    }
    __syncthreads();
    {
        float sum = 0.f;
        int k0 = pp*64;
        for (int k = k0; k < k0 + 64; ++k) sum = fmaf(s.hb[k], p.mo_w0[k*HH + c], sum);
        s.pr[pp][c] = sum;
    }
    __syncthreads();
    if (tid < HH) s.hb2[c] = fmaxf(s.pr[0][c] + s.pr[1][c] + p.mo_b0[c], 0.f);
    __syncthreads();
    {
        float sum = 0.f;
        int k0 = pp*64;
        for (int k = k0; k < k0 + 64; ++k) sum = fmaf(s.hb2[k], p.mo_w1[k*HH + c], sum);
        s.pr[pp][c] = sum;
    }
    __syncthreads();
    if (tid < HH) {
        float a3 = s.pr[0][c] + s.pr[1][c] + p.mo_b1[c];
        float mk = (p.poly_mask[bm] > 0.5f) ? 1.f : 0.f;
        float v = a3 * mk;
        p.map_node[(size_t)bm*HH + c] = v;
        int b = bm / MM, m = bm % MM;
        p.map_nodeT[((size_t)b*HH + c)*MM + m] = v;
    }
}

// ---------------- 1b: agent encoder (4 rows per block, 256 thr) ----------------
__device__ void do_agent_enc(const P& p, SAG& s, int r0) {
    int tid = threadIdx.x, h = tid >> 7, c = tid & 127;
    if (tid < 20) s.xin[tid/5][tid%5] = p.astate[(size_t)r0*5 + tid];
    __syncthreads();
    if (h == 0) {
        float b = p.ae_b0[c];
        float w[5];
        #pragma unroll
        for (int i = 0; i < 5; ++i) w[i] = p.ae_w0[i*HH + c];
        #pragma unroll
        for (int r = 0; r < 4; ++r) {
            float v = b;
            #pragma unroll
            for (int i = 0; i < 5; ++i) v = fmaf(s.xin[r][i], w[i], v);
            s.h1[r][c] = fmaxf(v, 0.f);
        }
    }
    __syncthreads();
    {
        float acc[4] = {0.f,0.f,0.f,0.f};
        int k0 = h*64;
        for (int k = k0; k < k0 + 64; ++k) {
            float wv = p.ae_w1[k*HH + c];
            #pragma unroll
            for (int r = 0; r < 4; ++r) acc[r] = fmaf(s.h1[r][k], wv, acc[r]);
        }
        #pragma unroll
        for (int r = 0; r < 4; ++r) s.p1[h][r][c] = acc[r];
    }
    __syncthreads();
    {
        #pragma unroll
        for (int rr = 0; rr < 2; ++rr) {
            int r = h*2 + rr;
            s.h2[r][c] = fmaxf(s.p1[0][r][c] + s.p1[1][r][c] + p.ae_b1[c], 0.f);
        }
    }
    __syncthreads();
    {
        float acc[4] = {0.f,0.f,0.f,0.f};
        int k0 = h*64;
        for (int k = k0; k < k0 + 64; ++k) {
            float wv = p.ae_w2[k*HH + c];
            #pragma unroll
            for (int r = 0; r < 4; ++r) acc[r] = fmaf(s.h2[r][k], wv, acc[r]);
        }
        #pragma unroll
        for (int r = 0; r < 4; ++r) s.p1[h][r][c] = acc[r];
    }
    __syncthreads();
    {
        #pragma unroll
        for (int rr = 0; rr < 2; ++rr) {
            int r = h*2 + rr;
            int row = r0 + r;
            p.a_emb[(size_t)row*HH + c] = (s.p1[0][r][c] + s.p1[1][r][c] + p.ae_b2[c]) * p.amask[row];
        }
    }
}

// ---------------- kernel A: encoders (960 blocks) ----------------
__global__ __launch_bounds__(256) void k_enc(P p) {
    __shared__ __align__(16) char smraw[(sizeof(SME) > sizeof(SAG)) ? sizeof(SME) : sizeof(SAG)];
    int task = blockIdx.x;
    if (task < BB*MM) do_map_enc(p, *(SME*)smraw, task);
    else              do_agent_enc(p, *(SAG*)smraw, (task - BB*MM)*4);
}

// ---------------- kernel B: fused map-attn + nbr-attn + tau ----------------
// 576 blocks, 256 thr; block = 4 n-rows at fixed (b,t): rows (b, n0..n0+3, t)
__global__ __launch_bounds__(256) void k_fat(P p) {
    __shared__ __align__(16) SF s;
    int task = blockIdx.x;
    int b    = task / (TT*12);
    int rem  = task % (TT*12);
    int t    = rem / 12;
    int n0   = (rem % 12) * 4;
    int tid  = threadIdx.x;

    int row0 = (b*NN + n0)*TT + t;          // row[r] = row0 + r*TT

    // ---- load queries (4 rows) + map weights ----
    for (int idx = tid; idx < 4*HH; idx += 256) {
        int r = idx >> 7, k = idx & 127;
        ((float*)&s.aq4L[k])[r] = p.a_emb[(size_t)(row0 + r*TT)*HH + k];
    }
    if (tid < HH) {
        int k = tid;
        s.u.m.w4L[k] = make_float4(p.mr_w0[k], p.mr_w0[HH+k], p.mr_w0[2*HH+k], p.mr_b0[k]);
        s.u.m.w1L[k] = p.mr_w1[k];
    }

    float rx[4], ry[4], rd[4];
    if (tid < MM) {
        float mcx = p.map_center[(b*MM + tid)*2];
        float mcy = p.map_center[(b*MM + tid)*2 + 1];
        #pragma unroll
        for (int r = 0; r < 4; ++r) {
            float px = p.astate[(size_t)(row0 + r*TT)*5];
            float py = p.astate[(size_t)(row0 + r*TT)*5 + 1];
            rx[r] = mcx - px; ry[r] = mcy - py;
            rd[r] = sqrtf(rx[r]*rx[r] + ry[r]*ry[r]);
        }
    }

    // ---- map phase A: chunk-staged logits (R3-proven structure) ----
    const float* mnT = p.map_nodeT + (size_t)b*HH*MM;
    float4 st[3];
    #pragma unroll
    for (int i = 0; i < 3; ++i) {
        int q = tid + 256*i;
        int kk = q / 48, mq = q % 48;
        st[i] = *(const float4*)(mnT + (size_t)kk*MM + mq*4);
    }
    float sacc[4] = {0.f,0.f,0.f,0.f};
    float dt4[4]  = {0.f,0.f,0.f,0.f};
    for (int ch = 0; ch < 8; ++ch) {
        __syncthreads();
        #pragma unroll
        for (int i = 0; i < 3; ++i) {
            int q = tid + 256*i;
            int kk = q / 48, mq = q % 48;
            *(float4*)&s.u.m.mnL[kk][mq*4] = st[i];
        }
        __syncthreads();
        if (ch < 7) {
            #pragma unroll
            for (int i = 0; i < 3; ++i) {
                int q = tid + 256*i;
                int kk = q / 48, mq = q % 48;
                st[i] = *(const float4*)(mnT + (size_t)(ch+1)*16*MM + (size_t)kk*MM + mq*4);
            }
        }
        if (tid < MM) {
            int k0 = ch*16;
            #pragma unroll
            for (int kk = 0; kk < 16; ++kk) {
                int k = k0 + kk;
                float4 w  = s.u.m.w4L[k];
                float  w1 = s.u.m.w1L[k];
                float4 aq = s.aq4L[k];
                float  mn = s.u.m.mnL[kk][tid];
                #pragma unroll
                for (int r = 0; r < 4; ++r) {
                    float hv = fmaf(rx[r], w.x, fmaf(ry[r], w.y, fmaf(rd[r], w.z, w.w)));
                    sacc[r] = fmaf(fmaxf(hv, 0.f), w1, sacc[r]);
                }
                dt4[0] = fmaf(aq.x, mn, dt4[0]);
                dt4[1] = fmaf(aq.y, mn, dt4[1]);
                dt4[2] = fmaf(aq.z, mn, dt4[2]);
                dt4[3] = fmaf(aq.w, mn, dt4[3]);
            }
        }
    }
    if (tid < MM) {
        float pm = p.poly_mask[b*MM + tid];
        float b1 = p.mr_b1[0];
        #pragma unroll
        for (int r = 0; r < 4; ++r) {
            float lgt = fmaf(dt4[r], RSQRT_H, sacc[r] + b1);
            s.u.m.lg[r][tid] = (pm > 0.5f) ? lgt : -1e9f;
        }
    }
    __syncthreads();

    // ---- map softmax: wave r handles row r ----
    {
        int r = tid >> 6, l = tid & 63;
        float v = fmaxf(fmaxf(s.u.m.lg[r][l], s.u.m.lg[r][l+64]), s.u.m.lg[r][l+128]);
        #pragma unroll
        for (int o = 32; o > 0; o >>= 1) v = fmaxf(v, __shfl_xor(v, o));
        float e0 = expf(s.u.m.lg[r][l] - v);
        float e1 = expf(s.u.m.lg[r][l+64] - v);
        float e2 = expf(s.u.m.lg[r][l+128] - v);
        s.u.m.lg[r][l] = e0; s.u.m.lg[r][l+64] = e1; s.u.m.lg[r][l+128] = e2;
        float sm = e0 + e1 + e2;
        #pragma unroll
        for (int o = 32; o > 0; o >>= 1) sm += __shfl_xor(sm, o);
        if (l == 0) s.u.m.invL[r] = 1.0f / sm;
    }
    __syncthreads();
    if (tid < MM) {
        s.u.m.p4L[tid] = make_float4(s.u.m.lg[0][tid]*s.u.m.invL[0], s.u.m.lg[1][tid]*s.u.m.invL[1],
                                     s.u.m.lg[2][tid]*s.u.m.invL[2], s.u.m.lg[3][tid]*s.u.m.invL[3]);
    }
    __syncthreads();

    // ---- map phase C: global map_node reads feed 4 rows ----
    {
        int half = tid >> 7, c = tid & 127;
        float a0=0.f, a1=0.f, a2=0.f, a3=0.f;
        const float* mnb = p.map_node + ((size_t)b*MM + half*96)*HH + c;
        for (int m = 0; m < 96; ++m) {
            float mv = mnb[(size_t)m*HH];
            float4 pp4 = s.u.m.p4L[half*96 + m];
            a0 = fmaf(pp4.x, mv, a0); a1 = fmaf(pp4.y, mv, a1);
            a2 = fmaf(pp4.z, mv, a2); a3 = fmaf(pp4.w, mv, a3);
        }
        s.pc[half][0][c]=a0; s.pc[half][1][c]=a1; s.pc[half][2][c]=a2; s.pc[half][3][c]=a3;
    }
    __syncthreads();
    for (int idx = tid; idx < 4*HH; idx += 256) {
        int r = idx >> 7, c = idx & 127;
        float v = s.pc[0][r][c] + s.pc[1][r][c];
        s.mctx[r][c] = v;
        p.map_ctx[(size_t)(row0 + r*TT)*HH + c] = v;
    }
    __syncthreads();   // u.m dead; safe to write u.n

    // ---- nbr phase: load agent positions + weights ----
    if (tid < NN) {
        int rj = (b*NN + tid)*TT + t;
        s.u.n.pjL[tid][0] = p.astate[(size_t)rj*5];
        s.u.n.pjL[tid][1] = p.astate[(size_t)rj*5 + 1];
        s.u.n.pjL[tid][2] = p.astate[(size_t)rj*5 + 3];
        s.u.n.pjL[tid][3] = p.astate[(size_t)rj*5 + 4];
        s.u.n.pjL[tid][4] = p.amask[rj];
    }
    if (tid < HH) {
        int k = tid;
        s.u.n.wAL[k] = make_float4(p.nr_w0[k], p.nr_w0[HH+k], p.nr_w0[2*HH+k], p.nr_w0[3*HH+k]);
        s.u.n.wBL[k] = make_float4(p.nr_w0[4*HH+k], p.nr_b0[k], p.nr_w1[k], 0.f);
    }
    __syncthreads();

    // ---- nbr phase A: thread (j, kg); a_emb rows read from L2 ----
    {
        int j  = tid % 48;
        int kg = tid / 48;
        if (kg < 4) {
            float jx = s.u.n.pjL[j][0], jy = s.u.n.pjL[j][1];
            float jvx = s.u.n.pjL[j][2], jvy = s.u.n.pjL[j][3];
            float dx[4], dy[4], dvx[4], dvy[4], dd[4];
            #pragma unroll
            for (int r = 0; r < 4; ++r) {
                int ni = n0 + r;
                dx[r]  = s.u.n.pjL[ni][0] - jx;  dy[r]  = s.u.n.pjL[ni][1] - jy;
                dvx[r] = s.u.n.pjL[ni][2] - jvx; dvy[r] = s.u.n.pjL[ni][3] - jvy;
                dd[r]  = sqrtf(dx[r]*dx[r] + dy[r]*dy[r]);
            }
            const float* aj = p.a_emb + ((size_t)(b*NN + j)*TT + t)*HH;
            float sr[4]  = {0,0,0,0};
            float dtn[4] = {0,0,0,0};
            int k0 = kg*32;
            for (int kk = 0; kk < 32; ++kk) {
                int k = k0 + kk;
                float4 wa = s.u.n.wAL[k], wb = s.u.n.wBL[k];
                float4 aq = s.aq4L[k];
                float  av = aj[k];
                #pragma unroll
                for (int r = 0; r < 4; ++r) {
                    float hv = fmaf(dx[r], wa.x, fmaf(dy[r], wa.y,
                               fmaf(dvx[r], wa.z, fmaf(dvy[r], wa.w,
                               fmaf(dd[r], wb.x, wb.y)))));
                    sr[r] = fmaf(fmaxf(hv, 0.f), wb.z, sr[r]);
                }
                dtn[0] = fmaf(aq.x, av, dtn[0]); dtn[1] = fmaf(aq.y, av, dtn[1]);
                dtn[2] = fmaf(aq.z, av, dtn[2]); dtn[3] = fmaf(aq.w, av, dtn[3]);
            }
            #pragma unroll
            for (int r = 0; r < 4; ++r) { s.u.n.sPL[kg][r][j] = sr[r]; s.u.n.dPL[kg][r][j] = dtn[r]; }
        }
    }
    __syncthreads();

    // ---- combine + mask ----
    {
        float b1 = p.nr_b1[0];
        for (int idx = tid; idx < 4*NN; idx += 256) {
            int r = idx / NN, jj = idx % NN;
            int ni = n0 + r;
            float ss  = s.u.n.sPL[0][r][jj] + s.u.n.sPL[1][r][jj] + s.u.n.sPL[2][r][jj] + s.u.n.sPL[3][r][jj] + b1;
            float do2 = s.u.n.dPL[0][r][jj] + s.u.n.dPL[1][r][jj] + s.u.n.dPL[2][r][jj] + s.u.n.dPL[3][r][jj];
            float ddx = s.u.n.pjL[ni][0] - s.u.n.pjL[jj][0];
            float ddy = s.u.n.pjL[ni][1] - s.u.n.pjL[jj][1];
            float dist = sqrtf(ddx*ddx + ddy*ddy);
            bool ok = (s.u.n.pjL[ni][4] > 0.5f) && (s.u.n.pjL[jj][4] > 0.5f) &&
                      (dist <= RADIUS_C) && (jj != ni);
            s.u.n.lgN[r][jj] = ok ? fmaf(do2, RSQRT_H, ss) : -1e9f;
        }
    }
    __syncthreads();

    // ---- nbr softmax: wave r handles row r ----
    {
        int r = tid >> 6, l = tid & 63;
        float v = (l < NN) ? s.u.n.lgN[r][l] : -3.4e38f;
        #pragma unroll
        for (int o = 32; o > 0; o >>= 1) v = fmaxf(v, __shfl_xor(v, o));
        float e = (l < NN) ? expf(s.u.n.lgN[r][l] - v) : 0.f;
        float sm = e;
        #pragma unroll
        for (int o = 32; o > 0; o >>= 1) sm += __shfl_xor(sm, o);
        if (l < NN) s.u.n.lgN[r][l] = e / sm;
    }
    __syncthreads();
    if (tid < NN) {
        s.u.n.pN[tid] = make_float4(s.u.n.lgN[0][tid], s.u.n.lgN[1][tid],
                                    s.u.n.lgN[2][tid], s.u.n.lgN[3][tid]);
    }
    __syncthreads();

    // ---- nbr phase C: global a_emb reads feed 4 rows ----
    {
        int half = tid >> 7, c = tid & 127;
        float a0=0.f, a1=0.f, a2=0.f, a3=0.f;
        for (int jj = half*24; jj < half*24 + 24; ++jj) {
            float av = p.a_emb[((size_t)(b*NN + jj)*TT + t)*HH + c];
            float4 pp4 = s.u.n.pN[jj];
            a0 = fmaf(pp4.x, av, a0); a1 = fmaf(pp4.y, av, a1);
            a2 = fmaf(pp4.z, av, a2); a3 = fmaf(pp4.w, av, a3);
        }
        s.pc[half][0][c]=a0; s.pc[half][1][c]=a1; s.pc[half][2][c]=a2; s.pc[half][3][c]=a3;
    }
    __syncthreads();
    for (int idx = tid; idx < 4*HH; idx += 256) {
        int r = idx >> 7, c = idx & 127;
        float v = s.pc[0][r][c] + s.pc[1][r][c];
        s.nctx[r][c] = v;
        p.nbr_ctx[(size_t)(row0 + r*TT)*HH + c] = v;
    }
    __syncthreads();   // u.n dead; safe to write u.t

    // ---- tau phase: inputs already in LDS (aq4L, mctx, nctx) ----
    for (int idx = tid; idx < 4*HH; idx += 256) {
        int r = idx >> 7, k = idx & 127;
        s.u.t.xinT[k][r]        = ((float*)&s.aq4L[k])[r];
        s.u.t.xinT[HH + k][r]   = s.mctx[r][k];
        s.u.t.xinT[2*HH + k][r] = s.nctx[r][k];
    }
    __syncthreads();
    {
        int c = tid & 127, h = tid >> 7;
        float acc[4] = {0,0,0,0};
        for (int k = h*192; k < h*192 + 192; ++k) {
            float wv = p.to_w0[k*HH + c];
            float4 xa = *(const float4*)&s.u.t.xinT[k][0];
            acc[0]=fmaf(xa.x,wv,acc[0]); acc[1]=fmaf(xa.y,wv,acc[1]);
            acc[2]=fmaf(xa.z,wv,acc[2]); acc[3]=fmaf(xa.w,wv,acc[3]);
        }
        #pragma unroll
        for (int r = 0; r < 4; ++r) s.pc[h][r][c] = acc[r];
    }
    __syncthreads();
    for (int idx = tid; idx < 4*HH; idx += 256) {
        int r = idx >> 7, k = idx & 127;
        s.u.t.h1T[k][r] = fmaxf(s.pc[0][r][k] + s.pc[1][r][k] + p.to_b0[k], 0.f);
    }
    __syncthreads();
    {
        int r = tid >> 6, c2 = tid & 63;
        float acc = p.to_b1[c2];
        for (int k = 0; k < HH; ++k)
            acc = fmaf(s.u.t.h1T[k][r], p.to_w1[k*64 + c2], acc);
        p.tau[(size_t)(row0 + r*TT)*64 + c2] = acc * p.amask[row0 + r*TT];
    }
}

extern "C" void kernel_launch(void* const* d_in, const int* in_sizes, int n_in,
                              void* d_out, int out_size, void* d_ws, size_t ws_size,
                              hipStream_t stream)
{
    P p;
    p.astate    = (const float*)d_in[0];
    p.amask     = (const float*)d_in[1];
    p.polylines = (const float*)d_in[2];
    p.poly_mask = (const float*)d_in[3];
    p.ptype     = (const int*)d_in[4];
    p.tlst      = (const int*)d_in[5];
    p.route     = (const int*)d_in[6];
    p.ae_w0 = (const float*)d_in[7];  p.ae_b0 = (const float*)d_in[8];
    p.ae_w1 = (const float*)d_in[9];  p.ae_b1 = (const float*)d_in[10];
    p.ae_w2 = (const float*)d_in[11]; p.ae_b2 = (const float*)d_in[12];
    p.mp_w0 = (const float*)d_in[13]; p.mp_b0 = (const float*)d_in[14];
    p.mp_w1 = (const float*)d_in[15]; p.mp_b1 = (const float*)d_in[16];
    p.type_emb  = (const float*)d_in[17];
    p.tl_emb    = (const float*)d_in[18];
    p.route_emb = (const float*)d_in[19];
    p.mo_w0 = (const float*)d_in[20]; p.mo_b0 = (const float*)d_in[21];
    p.mo_w1 = (const float*)d_in[22]; p.mo_b1 = (const float*)d_in[23];
    p.mr_w0 = (const float*)d_in[24]; p.mr_b0 = (const float*)d_in[25];
    p.mr_w1 = (const float*)d_in[26]; p.mr_b1 = (const float*)d_in[27];
    p.nr_w0 = (const float*)d_in[28]; p.nr_b0 = (const float*)d_in[29];
    p.nr_w1 = (const float*)d_in[30]; p.nr_b1 = (const float*)d_in[31];
    p.to_w0 = (const float*)d_in[32]; p.to_b0 = (const float*)d_in[33];
    p.to_w1 = (const float*)d_in[34]; p.to_b1 = (const float*)d_in[35];

    p.tau     = (float*)d_out;
    p.map_ctx = (float*)d_out + (size_t)NT*64;
    p.nbr_ctx = p.map_ctx + (size_t)NT*HH;

    float* ws    = (float*)d_ws;
    p.a_emb      = ws;                                   // NT*HH
    p.map_node   = p.a_emb + (size_t)NT*HH;              // B*M*HH
    p.map_nodeT  = p.map_node + (size_t)BB*MM*HH;        // B*HH*MM
    p.map_center = p.map_nodeT + (size_t)BB*MM*HH;       // B*M*2

    k_enc<<<BB*MM + NT/4, 256, 0, stream>>>(p);          // 384 + 576 = 960
    k_fat<<<BB*TT*12,     256, 0, stream>>>(p);          // 576
}

// Round 10
// 184.491 us; speedup vs baseline: 1.0262x; 1.0183x over previous
//
#include <hip/hip_runtime.h>
#include <math.h>

#define HH 128
#define BB 2
#define NN 48
#define TT 24
#define MM 192
#define LL 20
#define NT (BB*NN*TT)   /* 2304 */
#define RSQRT_H 0.08838834764831845f  /* 1/sqrt(128) */
#define RADIUS_C 30.0f

struct P {
    const float *astate, *amask, *polylines, *poly_mask;
    const int *ptype, *tlst, *route;
    const float *ae_w0,*ae_b0,*ae_w1,*ae_b1,*ae_w2,*ae_b2;
    const float *mp_w0,*mp_b0,*mp_w1,*mp_b1;
    const float *type_emb,*tl_emb,*route_emb;
    const float *mo_w0,*mo_b0,*mo_w1,*mo_b1;
    const float *mr_w0,*mr_b0,*mr_w1,*mr_b1;
    const float *nr_w0,*nr_b0,*nr_w1,*nr_b1;
    const float *to_w0,*to_b0,*to_w1,*to_b1;
    float *tau,*map_ctx,*nbr_ctx;
    float *a_emb,*map_node,*map_nodeT,*map_center;
};

// ---- k_enc LDS layouts ----
struct SME { float pts[LL*2]; float h1[LL][HH]; float mx[2][HH]; float hb[HH]; float pr[2][HH]; float hb2[HH]; };
struct SAG { float xin[2][5]; float h1[2][HH]; float h2[2][HH]; float p1[2][2][HH]; };

// ---- fused attn+tau LDS, 2 rows/block (~16 KB) ----
struct SF {
    float aqL[HH][2];       // query rows (persistent through tau)
    float mctx[2][HH];
    float nctx[2][HH];
    float pc[2][2][HH];     // partial accumulators, reused each phase
    union {
        struct {            // map-attention phase
            float4 w4L[HH];
            float  w1L[HH];
            float  lg[2][MM];
            float  p2[MM][2];
            float  invL[2];
        } m;
        struct {            // nbr-attention phase
            float  pjL[NN][8];
            float4 wAL[HH];
            float4 wBL[HH];
            float  sPL[4][2][NN];
            float  dPL[4][2][NN];
            float  lgN[2][NN];
            float  pN[NN][2];
        } n;
        struct {            // tau phase
            float  xinT[3*HH][2];
            float  h1T[HH][2];
        } t;
    } u;
};

// ---------------- 1a: map polyline encoder (one bm per block, 256 thr) ----------------
__device__ void do_map_enc(const P& p, SME& s, int bm) {
    int tid = threadIdx.x, pp = tid >> 7, c = tid & 127;
    if (tid < LL*2) s.pts[tid] = p.polylines[(size_t)bm*LL*2 + tid];
    __syncthreads();
    {
        float w0x = p.mp_w0[c], w0y = p.mp_w0[HH + c], b0 = p.mp_b0[c];
        #pragma unroll
        for (int i = 0; i < 10; ++i) {
            int pt_ = pp + 2*i;
            s.h1[pt_][c] = fmaxf(fmaf(s.pts[2*pt_], w0x, fmaf(s.pts[2*pt_+1], w0y, b0)), 0.f);
        }
    }
    if (tid < 2) {
        float sum = 0.f;
        for (int q = 0; q < LL; ++q) sum += s.pts[2*q + tid];
        p.map_center[bm*2 + tid] = sum * (1.0f / LL);
    }
    __syncthreads();
    {
        float acc[10];
        float b1 = p.mp_b1[c];
        #pragma unroll
        for (int i = 0; i < 10; ++i) acc[i] = b1;
        for (int k = 0; k < HH; ++k) {
            float wv = p.mp_w1[k*HH + c];
            #pragma unroll
            for (int i = 0; i < 10; ++i) acc[i] = fmaf(s.h1[pp + 2*i][k], wv, acc[i]);
        }
        float m10 = acc[0];
        #pragma unroll
        for (int i = 1; i < 10; ++i) m10 = fmaxf(m10, acc[i]);
        s.mx[pp][c] = m10;
    }
    __syncthreads();
    if (tid < HH) {
        float hm = fmaxf(fmaxf(s.mx[0][c], s.mx[1][c]), 0.f);
        int pt = p.ptype[bm]; pt = pt < 0 ? 0 : (pt > 3 ? 3 : pt);
        int tv = p.tlst[bm];  tv = tv < 0 ? 0 : (tv > 7 ? 7 : tv);
        int rv = p.route[bm]; rv = rv < 0 ? 0 : (rv > 1 ? 1 : rv);
        hm += p.type_emb[pt*HH + c] + p.tl_emb[tv*HH + c] + p.route_emb[rv*HH + c];
        s.hb[c] = hm;
    }
    __syncthreads();
    {
        float sum = 0.f;
        int k0 = pp*64;
        for (int k = k0; k < k0 + 64; ++k) sum = fmaf(s.hb[k], p.mo_w0[k*HH + c], sum);
        s.pr[pp][c] = sum;
    }
    __syncthreads();
    if (tid < HH) s.hb2[c] = fmaxf(s.pr[0][c] + s.pr[1][c] + p.mo_b0[c], 0.f);
    __syncthreads();
    {
        float sum = 0.f;
        int k0 = pp*64;
        for (int k = k0; k < k0 + 64; ++k) sum = fmaf(s.hb2[k], p.mo_w1[k*HH + c], sum);
        s.pr[pp][c] = sum;
    }
    __syncthreads();
    if (tid < HH) {
        float a3 = s.pr[0][c] + s.pr[1][c] + p.mo_b1[c];
        float mk = (p.poly_mask[bm] > 0.5f) ? 1.f : 0.f;
        float v = a3 * mk;
        p.map_node[(size_t)bm*HH + c] = v;
        int b = bm / MM, m = bm % MM;
        p.map_nodeT[((size_t)b*HH + c)*MM + m] = v;
    }
}

// ---------------- 1b: agent encoder (2 rows per block, 256 thr) ----------------
__device__ void do_agent_enc(const P& p, SAG& s, int r0) {
    int tid = threadIdx.x, h = tid >> 7, c = tid & 127;
    if (tid < 10) s.xin[tid/5][tid%5] = p.astate[(size_t)r0*5 + tid];
    __syncthreads();
    if (h == 0) {
        float b = p.ae_b0[c];
        float w[5];
        #pragma unroll
        for (int i = 0; i < 5; ++i) w[i] = p.ae_w0[i*HH + c];
        #pragma unroll
        for (int r = 0; r < 2; ++r) {
            float v = b;
            #pragma unroll
            for (int i = 0; i < 5; ++i) v = fmaf(s.xin[r][i], w[i], v);
            s.h1[r][c] = fmaxf(v, 0.f);
        }
    }
    __syncthreads();
    {
        float a0 = 0.f, a1 = 0.f;
        int k0 = h*64;
        for (int k = k0; k < k0 + 64; ++k) {
            float wv = p.ae_w1[k*HH + c];
            a0 = fmaf(s.h1[0][k], wv, a0);
            a1 = fmaf(s.h1[1][k], wv, a1);
        }
        s.p1[h][0][c] = a0; s.p1[h][1][c] = a1;
    }
    __syncthreads();
    {
        int r = h;
        s.h2[r][c] = fmaxf(s.p1[0][r][c] + s.p1[1][r][c] + p.ae_b1[c], 0.f);
    }
    __syncthreads();
    {
        float a0 = 0.f, a1 = 0.f;
        int k0 = h*64;
        for (int k = k0; k < k0 + 64; ++k) {
            float wv = p.ae_w2[k*HH + c];
            a0 = fmaf(s.h2[0][k], wv, a0);
            a1 = fmaf(s.h2[1][k], wv, a1);
        }
        s.p1[h][0][c] = a0; s.p1[h][1][c] = a1;
    }
    __syncthreads();
    {
        int r = h;
        int row = r0 + r;
        p.a_emb[(size_t)row*HH + c] = (s.p1[0][r][c] + s.p1[1][r][c] + p.ae_b2[c]) * p.amask[row];
    }
}

// ---------------- kernel A: encoders (384 + 1152 = 1536 blocks) ----------------
__global__ __launch_bounds__(256) void k_enc(P p) {
    __shared__ __align__(16) char smraw[(sizeof(SME) > sizeof(SAG)) ? sizeof(SME) : sizeof(SAG)];
    int task = blockIdx.x;
    if (task < BB*MM) do_map_enc(p, *(SME*)smraw, task);
    else              do_agent_enc(p, *(SAG*)smraw, (task - BB*MM)*2);
}

// ---------------- kernel B: fused map-attn + nbr-attn + tau ----------------
// 1152 blocks, 256 thr; block = 2 n-rows at fixed (b,t): rows (b, n0..n0+1, t)
__global__ __launch_bounds__(256) void k_fat(P p) {
    __shared__ __align__(16) SF s;
    int task = blockIdx.x;
    int b    = task / (TT*24);
    int rem  = task % (TT*24);
    int t    = rem / 24;
    int n0   = (rem % 24) * 2;
    int tid  = threadIdx.x;

    int row0 = (b*NN + n0)*TT + t;          // rows: row0, row0 + TT

    // ---- stage queries + map weights ----
    for (int idx = tid; idx < 2*HH; idx += 256) {
        int r = idx & 1, k = idx >> 1;
        s.aqL[k][r] = p.a_emb[(size_t)(row0 + r*TT)*HH + k];
    }
    if (tid < HH) {
        int k = tid;
        s.u.m.w4L[k] = make_float4(p.mr_w0[k], p.mr_w0[HH+k], p.mr_w0[2*HH+k], p.mr_b0[k]);
        s.u.m.w1L[k] = p.mr_w1[k];
    }

    float rx[2], ry[2], rd[2];
    if (tid < MM) {
        float mcx = p.map_center[(b*MM + tid)*2];
        float mcy = p.map_center[(b*MM + tid)*2 + 1];
        #pragma unroll
        for (int r = 0; r < 2; ++r) {
            float px = p.astate[(size_t)(row0 + r*TT)*5];
            float py = p.astate[(size_t)(row0 + r*TT)*5 + 1];
            rx[r] = mcx - px; ry[r] = mcy - py;
            rd[r] = sqrtf(rx[r]*rx[r] + ry[r]*ry[r]);
        }
    }
    __syncthreads();

    // ---- map phase A: direct L2 reads of mnT (coalesced over m), no staging ----
    if (tid < MM) {
        const float* mnc = p.map_nodeT + (size_t)b*HH*MM + tid;
        float sacc[2] = {0.f, 0.f};
        float dt2[2]  = {0.f, 0.f};
        #pragma unroll 8
        for (int k = 0; k < HH; ++k) {
            float4 w  = s.u.m.w4L[k];
            float  w1 = s.u.m.w1L[k];
            float  mn = mnc[(size_t)k*MM];
            float  aq0 = s.aqL[k][0], aq1 = s.aqL[k][1];
            #pragma unroll
            for (int r = 0; r < 2; ++r) {
                float hv = fmaf(rx[r], w.x, fmaf(ry[r], w.y, fmaf(rd[r], w.z, w.w)));
                sacc[r] = fmaf(fmaxf(hv, 0.f), w1, sacc[r]);
            }
            dt2[0] = fmaf(aq0, mn, dt2[0]);
            dt2[1] = fmaf(aq1, mn, dt2[1]);
        }
        float pm = p.poly_mask[b*MM + tid];
        float b1 = p.mr_b1[0];
        #pragma unroll
        for (int r = 0; r < 2; ++r) {
            float lgt = fmaf(dt2[r], RSQRT_H, sacc[r] + b1);
            s.u.m.lg[r][tid] = (pm > 0.5f) ? lgt : -1e9f;
        }
    }
    __syncthreads();

    // ---- map softmax: waves 0,1 handle rows 0,1 ----
    {
        int w = tid >> 6, l = tid & 63;
        if (w < 2) {
            int r = w;
            float v = fmaxf(fmaxf(s.u.m.lg[r][l], s.u.m.lg[r][l+64]), s.u.m.lg[r][l+128]);
            #pragma unroll
            for (int o = 32; o > 0; o >>= 1) v = fmaxf(v, __shfl_xor(v, o));
            float e0 = expf(s.u.m.lg[r][l] - v);
            float e1 = expf(s.u.m.lg[r][l+64] - v);
            float e2 = expf(s.u.m.lg[r][l+128] - v);
            s.u.m.lg[r][l] = e0; s.u.m.lg[r][l+64] = e1; s.u.m.lg[r][l+128] = e2;
            float sm = e0 + e1 + e2;
            #pragma unroll
            for (int o = 32; o > 0; o >>= 1) sm += __shfl_xor(sm, o);
            if (l == 0) s.u.m.invL[r] = 1.0f / sm;
        }
    }
    __syncthreads();
    if (tid < MM) {
        s.u.m.p2[tid][0] = s.u.m.lg[0][tid] * s.u.m.invL[0];
        s.u.m.p2[tid][1] = s.u.m.lg[1][tid] * s.u.m.invL[1];
    }
    __syncthreads();

    // ---- map phase C: each map_node load feeds 2 rows ----
    {
        int half = tid >> 7, c = tid & 127;
        float a0 = 0.f, a1 = 0.f;
        const float* mnb = p.map_node + ((size_t)b*MM + half*96)*HH + c;
        for (int m = 0; m < 96; ++m) {
            float mv = mnb[(size_t)m*HH];
            float p0 = s.u.m.p2[half*96 + m][0];
            float p1v = s.u.m.p2[half*96 + m][1];
            a0 = fmaf(p0, mv, a0); a1 = fmaf(p1v, mv, a1);
        }
        s.pc[half][0][c] = a0; s.pc[half][1][c] = a1;
    }
    __syncthreads();
    for (int idx = tid; idx < 2*HH; idx += 256) {
        int r = idx >> 7, c = idx & 127;
        float v = s.pc[0][r][c] + s.pc[1][r][c];
        s.mctx[r][c] = v;
        p.map_ctx[(size_t)(row0 + r*TT)*HH + c] = v;
    }
    __syncthreads();   // u.m dead

    // ---- nbr phase: stage positions + weights ----
    if (tid < NN) {
        int rj = (b*NN + tid)*TT + t;
        s.u.n.pjL[tid][0] = p.astate[(size_t)rj*5];
        s.u.n.pjL[tid][1] = p.astate[(size_t)rj*5 + 1];
        s.u.n.pjL[tid][2] = p.astate[(size_t)rj*5 + 3];
        s.u.n.pjL[tid][3] = p.astate[(size_t)rj*5 + 4];
        s.u.n.pjL[tid][4] = p.amask[rj];
    }
    if (tid < HH) {
        int k = tid;
        s.u.n.wAL[k] = make_float4(p.nr_w0[k], p.nr_w0[HH+k], p.nr_w0[2*HH+k], p.nr_w0[3*HH+k]);
        s.u.n.wBL[k] = make_float4(p.nr_w0[4*HH+k], p.nr_b0[k], p.nr_w1[k], 0.f);
    }
    __syncthreads();

    // ---- nbr phase A: thread (j, kg); a_emb from L2 ----
    {
        int j  = tid % 48;
        int kg = tid / 48;
        if (kg < 4) {
            float jx = s.u.n.pjL[j][0], jy = s.u.n.pjL[j][1];
            float jvx = s.u.n.pjL[j][2], jvy = s.u.n.pjL[j][3];
            float dx[2], dy[2], dvx[2], dvy[2], dd[2];
            #pragma unroll
            for (int r = 0; r < 2; ++r) {
                int ni = n0 + r;
                dx[r]  = s.u.n.pjL[ni][0] - jx;  dy[r]  = s.u.n.pjL[ni][1] - jy;
                dvx[r] = s.u.n.pjL[ni][2] - jvx; dvy[r] = s.u.n.pjL[ni][3] - jvy;
                dd[r]  = sqrtf(dx[r]*dx[r] + dy[r]*dy[r]);
            }
            const float* aj = p.a_emb + ((size_t)(b*NN + j)*TT + t)*HH;
            float sr[2]  = {0.f, 0.f};
            float dtn[2] = {0.f, 0.f};
            int k0 = kg*32;
            #pragma unroll 8
            for (int kk = 0; kk < 32; ++kk) {
                int k = k0 + kk;
                float4 wa = s.u.n.wAL[k], wb = s.u.n.wBL[k];
                float  av = aj[k];
                float  aq0 = s.aqL[k][0], aq1 = s.aqL[k][1];
                #pragma unroll
                for (int r = 0; r < 2; ++r) {
                    float hv = fmaf(dx[r], wa.x, fmaf(dy[r], wa.y,
                               fmaf(dvx[r], wa.z, fmaf(dvy[r], wa.w,
                               fmaf(dd[r], wb.x, wb.y)))));
                    sr[r] = fmaf(fmaxf(hv, 0.f), wb.z, sr[r]);
                }
                dtn[0] = fmaf(aq0, av, dtn[0]);
                dtn[1] = fmaf(aq1, av, dtn[1]);
            }
            #pragma unroll
            for (int r = 0; r < 2; ++r) { s.u.n.sPL[kg][r][j] = sr[r]; s.u.n.dPL[kg][r][j] = dtn[r]; }
        }
    }
    __syncthreads();

    // ---- combine + mask ----
    {
        float b1 = p.nr_b1[0];
        for (int idx = tid; idx < 2*NN; idx += 256) {
            int r = idx / NN, jj = idx % NN;
            int ni = n0 + r;
            float ss  = s.u.n.sPL[0][r][jj] + s.u.n.sPL[1][r][jj] + s.u.n.sPL[2][r][jj] + s.u.n.sPL[3][r][jj] + b1;
            float do2 = s.u.n.dPL[0][r][jj] + s.u.n.dPL[1][r][jj] + s.u.n.dPL[2][r][jj] + s.u.n.dPL[3][r][jj];
            float ddx = s.u.n.pjL[ni][0] - s.u.n.pjL[jj][0];
            float ddy = s.u.n.pjL[ni][1] - s.u.n.pjL[jj][1];
            float dist = sqrtf(ddx*ddx + ddy*ddy);
            bool ok = (s.u.n.pjL[ni][4] > 0.5f) && (s.u.n.pjL[jj][4] > 0.5f) &&
                      (dist <= RADIUS_C) && (jj != ni);
            s.u.n.lgN[r][jj] = ok ? fmaf(do2, RSQRT_H, ss) : -1e9f;
        }
    }
    __syncthreads();

    // ---- nbr softmax: waves 0,1 handle rows 0,1 ----
    {
        int w = tid >> 6, l = tid & 63;
        if (w < 2) {
            int r = w;
            float v = (l < NN) ? s.u.n.lgN[r][l] : -3.4e38f;
            #pragma unroll
            for (int o = 32; o > 0; o >>= 1) v = fmaxf(v, __shfl_xor(v, o));
            float e = (l < NN) ? expf(s.u.n.lgN[r][l] - v) : 0.f;
            float sm = e;
            #pragma unroll
            for (int o = 32; o > 0; o >>= 1) sm += __shfl_xor(sm, o);
            if (l < NN) s.u.n.lgN[r][l] = e / sm;
        }
    }
    __syncthreads();
    if (tid < NN) {
        s.u.n.pN[tid][0] = s.u.n.lgN[0][tid];
        s.u.n.pN[tid][1] = s.u.n.lgN[1][tid];
    }
    __syncthreads();

    // ---- nbr phase C: each a_emb load feeds 2 rows ----
    {
        int half = tid >> 7, c = tid & 127;
        float a0 = 0.f, a1 = 0.f;
        for (int jj = half*24; jj < half*24 + 24; ++jj) {
            float av = p.a_emb[((size_t)(b*NN + jj)*TT + t)*HH + c];
            a0 = fmaf(s.u.n.pN[jj][0], av, a0);
            a1 = fmaf(s.u.n.pN[jj][1], av, a1);
        }
        s.pc[half][0][c] = a0; s.pc[half][1][c] = a1;
    }
    __syncthreads();
    for (int idx = tid; idx < 2*HH; idx += 256) {
        int r = idx >> 7, c = idx & 127;
        float v = s.pc[0][r][c] + s.pc[1][r][c];
        s.nctx[r][c] = v;
        p.nbr_ctx[(size_t)(row0 + r*TT)*HH + c] = v;
    }
    __syncthreads();   // u.n dead

    // ---- tau phase: inputs from LDS ----
    for (int idx = tid; idx < 2*HH; idx += 256) {
        int r = idx & 1, k = idx >> 1;
        s.u.t.xinT[k][r]        = s.aqL[k][r];
        s.u.t.xinT[HH + k][r]   = s.mctx[r][k];
        s.u.t.xinT[2*HH + k][r] = s.nctx[r][k];
    }
    __syncthreads();
    {
        int c = tid & 127, h = tid >> 7;
        float a0 = 0.f, a1 = 0.f;
        #pragma unroll 8
        for (int k = h*192; k < h*192 + 192; ++k) {
            float wv = p.to_w0[k*HH + c];
            float x0 = s.u.t.xinT[k][0], x1 = s.u.t.xinT[k][1];
            a0 = fmaf(x0, wv, a0);
            a1 = fmaf(x1, wv, a1);
        }
        s.pc[h][0][c] = a0; s.pc[h][1][c] = a1;
    }
    __syncthreads();
    for (int idx = tid; idx < 2*HH; idx += 256) {
        int r = idx & 1, k = idx >> 1;
        s.u.t.h1T[k][r] = fmaxf(s.pc[0][r][k] + s.pc[1][r][k] + p.to_b0[k], 0.f);
    }
    __syncthreads();
    {
        int kh = tid >> 7, rc = tid & 127;
        int r = rc >> 6, c2 = rc & 63;
        float acc = 0.f;
        for (int k = kh*64; k < kh*64 + 64; ++k)
            acc = fmaf(s.u.t.h1T[k][r], p.to_w1[k*64 + c2], acc);
        s.pc[kh][r][c2] = acc;
    }
    __syncthreads();
    if (tid < 128) {
        int r = tid >> 6, c2 = tid & 63;
        int row = row0 + r*TT;
        float v = (s.pc[0][r][c2] + s.pc[1][r][c2] + p.to_b1[c2]) * p.amask[row];
        p.tau[(size_t)row*64 + c2] = v;
    }
}

extern "C" void kernel_launch(void* const* d_in, const int* in_sizes, int n_in,
                              void* d_out, int out_size, void* d_ws, size_t ws_size,
                              hipStream_t stream)
{
    P p;
    p.astate    = (const float*)d_in[0];
    p.amask     = (const float*)d_in[1];
    p.polylines = (const float*)d_in[2];
    p.poly_mask = (const float*)d_in[3];
    p.ptype     = (const int*)d_in[4];
    p.tlst      = (const int*)d_in[5];
    p.route     = (const int*)d_in[6];
    p.ae_w0 = (const float*)d_in[7];  p.ae_b0 = (const float*)d_in[8];
    p.ae_w1 = (const float*)d_in[9];  p.ae_b1 = (const float*)d_in[10];
    p.ae_w2 = (const float*)d_in[11]; p.ae_b2 = (const float*)d_in[12];
    p.mp_w0 = (const float*)d_in[13]; p.mp_b0 = (const float*)d_in[14];
    p.mp_w1 = (const float*)d_in[15]; p.mp_b1 = (const float*)d_in[16];
    p.type_emb  = (const float*)d_in[17];
    p.tl_emb    = (const float*)d_in[18];
    p.route_emb = (const float*)d_in[19];
    p.mo_w0 = (const float*)d_in[20]; p.mo_b0 = (const float*)d_in[21];
    p.mo_w1 = (const float*)d_in[22]; p.mo_b1 = (const float*)d_in[23];
    p.mr_w0 = (const float*)d_in[24]; p.mr_b0 = (const float*)d_in[25];
    p.mr_w1 = (const float*)d_in[26]; p.mr_b1 = (const float*)d_in[27];
    p.nr_w0 = (const float*)d_in[28]; p.nr_b0 = (const float*)d_in[29];
    p.nr_w1 = (const float*)d_in[30]; p.nr_b1 = (const float*)d_in[31];
    p.to_w0 = (const float*)d_in[32]; p.to_b0 = (const float*)d_in[33];
    p.to_w1 = (const float*)d_in[34]; p.to_b1 = (const float*)d_in[35];

    p.tau     = (float*)d_out;
    p.map_ctx = (float*)d_out + (size_t)NT*64;
    p.nbr_ctx = p.map_ctx + (size_t)NT*HH;

    float* ws    = (float*)d_ws;
    p.a_emb      = ws;                                   // NT*HH
    p.map_node   = p.a_emb + (size_t)NT*HH;              // B*M*HH
    p.map_nodeT  = p.map_node + (size_t)BB*MM*HH;        // B*HH*MM
    p.map_center = p.map_nodeT + (size_t)BB*MM*HH;       // B*M*2

    k_enc<<<BB*MM + NT/2, 256, 0, stream>>>(p);          // 384 + 1152 = 1536
    k_fat<<<BB*TT*24,     256, 0, stream>>>(p);          // 1152
}

// Round 11
// 184.198 us; speedup vs baseline: 1.0278x; 1.0016x over previous
//
#include <hip/hip_runtime.h>
#include <math.h>

#define HH 128
#define BB 2
#define NN 48
#define TT 24
#define MM 192
#define LL 20
#define NT (BB*NN*TT)   /* 2304 */
#define RSQRT_H 0.08838834764831845f  /* 1/sqrt(128) */
#define RADIUS_C 30.0f

struct P {
    const float *astate, *amask, *polylines, *poly_mask;
    const int *ptype, *tlst, *route;
    const float *ae_w0,*ae_b0,*ae_w1,*ae_b1,*ae_w2,*ae_b2;
    const float *mp_w0,*mp_b0,*mp_w1,*mp_b1;
    const float *type_emb,*tl_emb,*route_emb;
    const float *mo_w0,*mo_b0,*mo_w1,*mo_b1;
    const float *mr_w0,*mr_b0,*mr_w1,*mr_b1;
    const float *nr_w0,*nr_b0,*nr_w1,*nr_b1;
    const float *to_w0,*to_b0,*to_w1,*to_b1;
    float *tau,*map_ctx,*nbr_ctx;
    float *a_emb,*map_node,*map_nodeT,*map_center;
};

// ---- k_enc LDS layouts ----
struct SME { float pts[LL*2]; float h1T[HH][LL]; float mx[2][HH]; float hb[HH]; float pr[2][HH]; float hb2[HH]; };
struct SAG { float xin[2][5]; float h1[2][HH]; float h2[2][HH]; float p1[2][2][HH]; };

// ---- fused attn+tau LDS, 4 rows/block (~23 KB) ----
struct SF {
    float4 aq4L[HH];        // [k] -> 4 query rows (persistent through tau)
    float  mctx[4][HH];
    float  nctx[4][HH];
    float  pc[2][4][HH];    // partial accumulators, reused each phase
    union {
        struct {            // map-attention phase
            float4 w4L[HH];
            float  w1L[HH];
            float  lg[4][MM];
            float4 p4L[MM];
            float  invL[4];
        } m;
        struct {            // nbr-attention phase
            float  pjL[NN][8];
            float4 wAL[HH];
            float4 wBL[HH];
            float  sPL[4][4][NN];
            float  dPL[4][4][NN];
            float  lgN[4][NN];
            float4 pN[NN];
        } n;
        struct {            // tau phase
            float4 xinT[3*HH];   // [k] -> 4 rows
            float4 h1T[HH];      // [k] -> 4 rows
        } t;
    } u;
};

// ---------------- 1a: map polyline encoder (one bm per block, 256 thr) ----------------
__device__ void do_map_enc(const P& p, SME& s, int bm) {
    int tid = threadIdx.x, pp = tid >> 7, c = tid & 127;
    if (tid < LL*2) s.pts[tid] = p.polylines[(size_t)bm*LL*2 + tid];
    __syncthreads();
    // layer0: lane (pp,c) computes points pp*10 .. pp*10+9, stores TRANSPOSED h1T[c][pt]
    {
        float w0x = p.mp_w0[c], w0y = p.mp_w0[HH + c], b0 = p.mp_b0[c];
        #pragma unroll
        for (int i = 0; i < 10; ++i) {
            int pt_ = pp*10 + i;
            s.h1T[c][pt_] = fmaxf(fmaf(s.pts[2*pt_], w0x, fmaf(s.pts[2*pt_+1], w0y, b0)), 0.f);
        }
    }
    if (tid < 2) {
        float sum = 0.f;
        for (int q = 0; q < LL; ++q) sum += s.pts[2*q + tid];
        p.map_center[bm*2 + tid] = sum * (1.0f / LL);
    }
    __syncthreads();
    // layer1 + maxpool: group pp handles its 10 points; reads h1T[k][pp*10..+9] (contiguous)
    {
        float acc[10];
        float b1 = p.mp_b1[c];
        #pragma unroll
        for (int i = 0; i < 10; ++i) acc[i] = b1;
        for (int k = 0; k < HH; ++k) {
            float wv = p.mp_w1[k*HH + c];
            const float* hrow = &s.h1T[k][pp*10];
            #pragma unroll
            for (int i = 0; i < 10; ++i) acc[i] = fmaf(hrow[i], wv, acc[i]);
        }
        float m10 = acc[0];
        #pragma unroll
        for (int i = 1; i < 10; ++i) m10 = fmaxf(m10, acc[i]);
        s.mx[pp][c] = m10;
    }
    __syncthreads();
    if (tid < HH) {
        float hm = fmaxf(fmaxf(s.mx[0][c], s.mx[1][c]), 0.f);
        int pt = p.ptype[bm]; pt = pt < 0 ? 0 : (pt > 3 ? 3 : pt);
        int tv = p.tlst[bm];  tv = tv < 0 ? 0 : (tv > 7 ? 7 : tv);
        int rv = p.route[bm]; rv = rv < 0 ? 0 : (rv > 1 ? 1 : rv);
        hm += p.type_emb[pt*HH + c] + p.tl_emb[tv*HH + c] + p.route_emb[rv*HH + c];
        s.hb[c] = hm;
    }
    __syncthreads();
    {
        float sum = 0.f;
        int k0 = pp*64;
        for (int k = k0; k < k0 + 64; ++k) sum = fmaf(s.hb[k], p.mo_w0[k*HH + c], sum);
        s.pr[pp][c] = sum;
    }
    __syncthreads();
    if (tid < HH) s.hb2[c] = fmaxf(s.pr[0][c] + s.pr[1][c] + p.mo_b0[c], 0.f);
    __syncthreads();
    {
        float sum = 0.f;
        int k0 = pp*64;
        for (int k = k0; k < k0 + 64; ++k) sum = fmaf(s.hb2[k], p.mo_w1[k*HH + c], sum);
        s.pr[pp][c] = sum;
    }
    __syncthreads();
    if (tid < HH) {
        float a3 = s.pr[0][c] + s.pr[1][c] + p.mo_b1[c];
        float mk = (p.poly_mask[bm] > 0.5f) ? 1.f : 0.f;
        float v = a3 * mk;
        p.map_node[(size_t)bm*HH + c] = v;
        int b = bm / MM, m = bm % MM;
        p.map_nodeT[((size_t)b*HH + c)*MM + m] = v;
    }
}

// ---------------- 1b: agent encoder (2 rows per block, 256 thr) ----------------
__device__ void do_agent_enc(const P& p, SAG& s, int r0) {
    int tid = threadIdx.x, h = tid >> 7, c = tid & 127;
    if (tid < 10) s.xin[tid/5][tid%5] = p.astate[(size_t)r0*5 + tid];
    __syncthreads();
    if (h == 0) {
        float b = p.ae_b0[c];
        float w[5];
        #pragma unroll
        for (int i = 0; i < 5; ++i) w[i] = p.ae_w0[i*HH + c];
        #pragma unroll
        for (int r = 0; r < 2; ++r) {
            float v = b;
            #pragma unroll
            for (int i = 0; i < 5; ++i) v = fmaf(s.xin[r][i], w[i], v);
            s.h1[r][c] = fmaxf(v, 0.f);
        }
    }
    __syncthreads();
    {
        float a0 = 0.f, a1 = 0.f;
        int k0 = h*64;
        for (int k = k0; k < k0 + 64; ++k) {
            float wv = p.ae_w1[k*HH + c];
            a0 = fmaf(s.h1[0][k], wv, a0);
            a1 = fmaf(s.h1[1][k], wv, a1);
        }
        s.p1[h][0][c] = a0; s.p1[h][1][c] = a1;
    }
    __syncthreads();
    {
        int r = h;
        s.h2[r][c] = fmaxf(s.p1[0][r][c] + s.p1[1][r][c] + p.ae_b1[c], 0.f);
    }
    __syncthreads();
    {
        float a0 = 0.f, a1 = 0.f;
        int k0 = h*64;
        for (int k = k0; k < k0 + 64; ++k) {
            float wv = p.ae_w2[k*HH + c];
            a0 = fmaf(s.h2[0][k], wv, a0);
            a1 = fmaf(s.h2[1][k], wv, a1);
        }
        s.p1[h][0][c] = a0; s.p1[h][1][c] = a1;
    }
    __syncthreads();
    {
        int r = h;
        int row = r0 + r;
        p.a_emb[(size_t)row*HH + c] = (s.p1[0][r][c] + s.p1[1][r][c] + p.ae_b2[c]) * p.amask[row];
    }
}

// ---------------- kernel A: encoders (384 + 1152 = 1536 blocks) ----------------
__global__ __launch_bounds__(256) void k_enc(P p) {
    __shared__ __align__(16) char smraw[(sizeof(SME) > sizeof(SAG)) ? sizeof(SME) : sizeof(SAG)];
    int task = blockIdx.x;
    if (task < BB*MM) do_map_enc(p, *(SME*)smraw, task);
    else              do_agent_enc(p, *(SAG*)smraw, (task - BB*MM)*2);
}

// ---------------- kernel B: fused map-attn + nbr-attn + tau ----------------
// 576 blocks, 256 thr; block = 4 n-rows at fixed (b,t): rows (b, n0..n0+3, t)
__global__ __launch_bounds__(256) void k_fat(P p) {
    __shared__ __align__(16) SF s;
    int task = blockIdx.x;
    int b    = task / (TT*12);
    int rem  = task % (TT*12);
    int t    = rem / 12;
    int n0   = (rem % 12) * 4;
    int tid  = threadIdx.x;

    int row0 = (b*NN + n0)*TT + t;          // row(r) = row0 + r*TT

    // ---- stage queries (4 rows packed per k) + map weights ----
    for (int idx = tid; idx < 4*HH; idx += 256) {
        int r = idx >> 7, k = idx & 127;
        ((float*)&s.aq4L[k])[r] = p.a_emb[(size_t)(row0 + r*TT)*HH + k];
    }
    if (tid < HH) {
        int k = tid;
        s.u.m.w4L[k] = make_float4(p.mr_w0[k], p.mr_w0[HH+k], p.mr_w0[2*HH+k], p.mr_b0[k]);
        s.u.m.w1L[k] = p.mr_w1[k];
    }

    float rx[4], ry[4], rd[4];
    if (tid < MM) {
        float mcx = p.map_center[(b*MM + tid)*2];
        float mcy = p.map_center[(b*MM + tid)*2 + 1];
        #pragma unroll
        for (int r = 0; r < 4; ++r) {
            float px = p.astate[(size_t)(row0 + r*TT)*5];
            float py = p.astate[(size_t)(row0 + r*TT)*5 + 1];
            rx[r] = mcx - px; ry[r] = mcy - py;
            rd[r] = sqrtf(rx[r]*rx[r] + ry[r]*ry[r]);
        }
    }
    __syncthreads();

    // ---- map phase A: direct L2 reads of mnT, vectorized LDS reads ----
    if (tid < MM) {
        const float* mnc = p.map_nodeT + (size_t)b*HH*MM + tid;
        float sacc[4] = {0.f,0.f,0.f,0.f};
        float dt4[4]  = {0.f,0.f,0.f,0.f};
        const float4* w1q4 = (const float4*)s.u.m.w1L;
        for (int kq = 0; kq < HH/4; ++kq) {
            float4 w1q = w1q4[kq];            // 4 k's of w1 in one read
            #pragma unroll
            for (int j = 0; j < 4; ++j) {
                int k = kq*4 + j;
                float4 w  = s.u.m.w4L[k];
                float4 aq = s.aq4L[k];
                float  w1 = ((const float*)&w1q)[j];
                float  mn = mnc[(size_t)k*MM];
                #pragma unroll
                for (int r = 0; r < 4; ++r) {
                    float hv = fmaf(rx[r], w.x, fmaf(ry[r], w.y, fmaf(rd[r], w.z, w.w)));
                    sacc[r] = fmaf(fmaxf(hv, 0.f), w1, sacc[r]);
                }
                dt4[0] = fmaf(aq.x, mn, dt4[0]);
                dt4[1] = fmaf(aq.y, mn, dt4[1]);
                dt4[2] = fmaf(aq.z, mn, dt4[2]);
                dt4[3] = fmaf(aq.w, mn, dt4[3]);
            }
        }
        float pm = p.poly_mask[b*MM + tid];
        float b1 = p.mr_b1[0];
        #pragma unroll
        for (int r = 0; r < 4; ++r) {
            float lgt = fmaf(dt4[r], RSQRT_H, sacc[r] + b1);
            s.u.m.lg[r][tid] = (pm > 0.5f) ? lgt : -1e9f;
        }
    }
    __syncthreads();

    // ---- map softmax: wave r handles row r (4 waves) ----
    {
        int r = tid >> 6, l = tid & 63;
        float v = fmaxf(fmaxf(s.u.m.lg[r][l], s.u.m.lg[r][l+64]), s.u.m.lg[r][l+128]);
        #pragma unroll
        for (int o = 32; o > 0; o >>= 1) v = fmaxf(v, __shfl_xor(v, o));
        float e0 = expf(s.u.m.lg[r][l] - v);
        float e1 = expf(s.u.m.lg[r][l+64] - v);
        float e2 = expf(s.u.m.lg[r][l+128] - v);
        s.u.m.lg[r][l] = e0; s.u.m.lg[r][l+64] = e1; s.u.m.lg[r][l+128] = e2;
        float sm = e0 + e1 + e2;
        #pragma unroll
        for (int o = 32; o > 0; o >>= 1) sm += __shfl_xor(sm, o);
        if (l == 0) s.u.m.invL[r] = 1.0f / sm;
    }
    __syncthreads();
    if (tid < MM) {
        s.u.m.p4L[tid] = make_float4(s.u.m.lg[0][tid]*s.u.m.invL[0], s.u.m.lg[1][tid]*s.u.m.invL[1],
                                     s.u.m.lg[2][tid]*s.u.m.invL[2], s.u.m.lg[3][tid]*s.u.m.invL[3]);
    }
    __syncthreads();

    // ---- map phase C: each map_node load feeds 4 rows ----
    {
        int half = tid >> 7, c = tid & 127;
        float a0=0.f, a1=0.f, a2=0.f, a3=0.f;
        const float* mnb = p.map_node + ((size_t)b*MM + half*96)*HH + c;
        for (int m = 0; m < 96; ++m) {
            float mv = mnb[(size_t)m*HH];
            float4 pp4 = s.u.m.p4L[half*96 + m];
            a0 = fmaf(pp4.x, mv, a0); a1 = fmaf(pp4.y, mv, a1);
            a2 = fmaf(pp4.z, mv, a2); a3 = fmaf(pp4.w, mv, a3);
        }
        s.pc[half][0][c]=a0; s.pc[half][1][c]=a1; s.pc[half][2][c]=a2; s.pc[half][3][c]=a3;
    }
    __syncthreads();
    for (int idx = tid; idx < 4*HH; idx += 256) {
        int r = idx >> 7, c = idx & 127;
        float v = s.pc[0][r][c] + s.pc[1][r][c];
        s.mctx[r][c] = v;
        p.map_ctx[(size_t)(row0 + r*TT)*HH + c] = v;
    }
    __syncthreads();   // u.m dead

    // ---- nbr phase: stage positions + weights ----
    if (tid < NN) {
        int rj = (b*NN + tid)*TT + t;
        s.u.n.pjL[tid][0] = p.astate[(size_t)rj*5];
        s.u.n.pjL[tid][1] = p.astate[(size_t)rj*5 + 1];
        s.u.n.pjL[tid][2] = p.astate[(size_t)rj*5 + 3];
        s.u.n.pjL[tid][3] = p.astate[(size_t)rj*5 + 4];
        s.u.n.pjL[tid][4] = p.amask[rj];
    }
    if (tid < HH) {
        int k = tid;
        s.u.n.wAL[k] = make_float4(p.nr_w0[k], p.nr_w0[HH+k], p.nr_w0[2*HH+k], p.nr_w0[3*HH+k]);
        s.u.n.wBL[k] = make_float4(p.nr_w0[4*HH+k], p.nr_b0[k], p.nr_w1[k], 0.f);
    }
    __syncthreads();

    // ---- nbr phase A: thread (j, kg); a_emb from L2; 4 rows per thread ----
    {
        int j  = tid % 48;
        int kg = tid / 48;
        if (kg < 4) {
            float jx = s.u.n.pjL[j][0], jy = s.u.n.pjL[j][1];
            float jvx = s.u.n.pjL[j][2], jvy = s.u.n.pjL[j][3];
            float dx[4], dy[4], dvx[4], dvy[4], dd[4];
            #pragma unroll
            for (int r = 0; r < 4; ++r) {
                int ni = n0 + r;
                dx[r]  = s.u.n.pjL[ni][0] - jx;  dy[r]  = s.u.n.pjL[ni][1] - jy;
                dvx[r] = s.u.n.pjL[ni][2] - jvx; dvy[r] = s.u.n.pjL[ni][3] - jvy;
                dd[r]  = sqrtf(dx[r]*dx[r] + dy[r]*dy[r]);
            }
            const float* aj = p.a_emb + ((size_t)(b*NN + j)*TT + t)*HH;
            float sr[4]  = {0.f,0.f,0.f,0.f};
            float dtn[4] = {0.f,0.f,0.f,0.f};
            int k0 = kg*32;
            #pragma unroll 4
            for (int kk = 0; kk < 32; ++kk) {
                int k = k0 + kk;
                float4 wa = s.u.n.wAL[k], wb = s.u.n.wBL[k];
                float4 aq = s.aq4L[k];
                float  av = aj[k];
                #pragma unroll
                for (int r = 0; r < 4; ++r) {
                    float hv = fmaf(dx[r], wa.x, fmaf(dy[r], wa.y,
                               fmaf(dvx[r], wa.z, fmaf(dvy[r], wa.w,
                               fmaf(dd[r], wb.x, wb.y)))));
                    sr[r] = fmaf(fmaxf(hv, 0.f), wb.z, sr[r]);
                }
                dtn[0] = fmaf(aq.x, av, dtn[0]); dtn[1] = fmaf(aq.y, av, dtn[1]);
                dtn[2] = fmaf(aq.z, av, dtn[2]); dtn[3] = fmaf(aq.w, av, dtn[3]);
            }
            #pragma unroll
            for (int r = 0; r < 4; ++r) { s.u.n.sPL[kg][r][j] = sr[r]; s.u.n.dPL[kg][r][j] = dtn[r]; }
        }
    }
    __syncthreads();

    // ---- combine + mask ----
    {
        float b1 = p.nr_b1[0];
        for (int idx = tid; idx < 4*NN; idx += 256) {
            int r = idx / NN, jj = idx % NN;
            int ni = n0 + r;
            float ss  = s.u.n.sPL[0][r][jj] + s.u.n.sPL[1][r][jj] + s.u.n.sPL[2][r][jj] + s.u.n.sPL[3][r][jj] + b1;
            float do2 = s.u.n.dPL[0][r][jj] + s.u.n.dPL[1][r][jj] + s.u.n.dPL[2][r][jj] + s.u.n.dPL[3][r][jj];
            float ddx = s.u.n.pjL[ni][0] - s.u.n.pjL[jj][0];
            float ddy = s.u.n.pjL[ni][1] - s.u.n.pjL[jj][1];
            float dist = sqrtf(ddx*ddx + ddy*ddy);
            bool ok = (s.u.n.pjL[ni][4] > 0.5f) && (s.u.n.pjL[jj][4] > 0.5f) &&
                      (dist <= RADIUS_C) && (jj != ni);
            s.u.n.lgN[r][jj] = ok ? fmaf(do2, RSQRT_H, ss) : -1e9f;
        }
    }
    __syncthreads();

    // ---- nbr softmax: wave r handles row r ----
    {
        int r = tid >> 6, l = tid & 63;
        float v = (l < NN) ? s.u.n.lgN[r][l] : -3.4e38f;
        #pragma unroll
        for (int o = 32; o > 0; o >>= 1) v = fmaxf(v, __shfl_xor(v, o));
        float e = (l < NN) ? expf(s.u.n.lgN[r][l] - v) : 0.f;
        float sm = e;
        #pragma unroll
        for (int o = 32; o > 0; o >>= 1) sm += __shfl_xor(sm, o);
        if (l < NN) s.u.n.lgN[r][l] = e / sm;
    }
    __syncthreads();
    if (tid < NN) {
        s.u.n.pN[tid] = make_float4(s.u.n.lgN[0][tid], s.u.n.lgN[1][tid],
                                    s.u.n.lgN[2][tid], s.u.n.lgN[3][tid]);
    }
    __syncthreads();

    // ---- nbr phase C: each a_emb load feeds 4 rows ----
    {
        int half = tid >> 7, c = tid & 127;
        float a0=0.f, a1=0.f, a2=0.f, a3=0.f;
        for (int jj = half*24; jj < half*24 + 24; ++jj) {
            float av = p.a_emb[((size_t)(b*NN + jj)*TT + t)*HH + c];
            float4 pp4 = s.u.n.pN[jj];
            a0 = fmaf(pp4.x, av, a0); a1 = fmaf(pp4.y, av, a1);
            a2 = fmaf(pp4.z, av, a2); a3 = fmaf(pp4.w, av, a3);
        }
        s.pc[half][0][c]=a0; s.pc[half][1][c]=a1; s.pc[half][2][c]=a2; s.pc[half][3][c]=a3;
    }
    __syncthreads();
    for (int idx = tid; idx < 4*HH; idx += 256) {
        int r = idx >> 7, c = idx & 127;
        float v = s.pc[0][r][c] + s.pc[1][r][c];
        s.nctx[r][c] = v;
        p.nbr_ctx[(size_t)(row0 + r*TT)*HH + c] = v;
    }
    __syncthreads();   // u.n dead

    // ---- tau phase: pack xinT[k] = 4 rows per float4 ----
    for (int idx = tid; idx < 3*HH; idx += 256) {
        if (idx < HH) {
            s.u.t.xinT[idx] = s.aq4L[idx];
        } else if (idx < 2*HH) {
            int k = idx - HH;
            s.u.t.xinT[idx] = make_float4(s.mctx[0][k], s.mctx[1][k], s.mctx[2][k], s.mctx[3][k]);
        } else {
            int k = idx - 2*HH;
            s.u.t.xinT[idx] = make_float4(s.nctx[0][k], s.nctx[1][k], s.nctx[2][k], s.nctx[3][k]);
        }
    }
    __syncthreads();
    {
        int c = tid & 127, h = tid >> 7;
        float acc[4] = {0,0,0,0};
        for (int k = h*192; k < h*192 + 192; ++k) {
            float wv = p.to_w0[k*HH + c];
            float4 x4 = s.u.t.xinT[k];
            acc[0]=fmaf(x4.x,wv,acc[0]); acc[1]=fmaf(x4.y,wv,acc[1]);
            acc[2]=fmaf(x4.z,wv,acc[2]); acc[3]=fmaf(x4.w,wv,acc[3]);
        }
        #pragma unroll
        for (int r = 0; r < 4; ++r) s.pc[h][r][c] = acc[r];
    }
    __syncthreads();
    for (int idx = tid; idx < 4*HH; idx += 256) {
        int r = idx >> 7, k = idx & 127;
        ((float*)&s.u.t.h1T[k])[r] = fmaxf(s.pc[0][r][k] + s.pc[1][r][k] + p.to_b0[k], 0.f);
    }
    __syncthreads();
    {
        int kh = tid >> 7, rc = tid & 127;
        int r = rc >> 6, c2 = rc & 63;
        float acc = 0.f;
        for (int k = kh*64; k < kh*64 + 64; ++k)
            acc = fmaf(((const float*)&s.u.t.h1T[k])[r], p.to_w1[k*64 + c2], acc);
        s.pc[kh][r][c2] = acc;
    }
    __syncthreads();
    if (tid < 128) {
        int r = tid >> 6, c2 = tid & 63;
        int row = row0 + r*TT;
        float v = (s.pc[0][r][c2] + s.pc[1][r][c2] + p.to_b1[c2]) * p.amask[row];
        p.tau[(size_t)row*64 + c2] = v;
    }
    __syncthreads();
    if (tid < 128) {
        int r = 2 + (tid >> 6), c2 = tid & 63;
        int row = row0 + r*TT;
        float acc = 0.f;
        for (int k = 0; k < HH; ++k)
            acc = fmaf(((const float*)&s.u.t.h1T[k])[r], p.to_w1[k*64 + c2], acc);
        float v = (acc + p.to_b1[c2]) * p.amask[row];
        p.tau[(size_t)row*64 + c2] = v;
    }
}

extern "C" void kernel_launch(void* const* d_in, const int* in_sizes, int n_in,
                              void* d_out, int out_size, void* d_ws, size_t ws_size,
                              hipStream_t stream)
{
    P p;
    p.astate    = (const float*)d_in[0];
    p.amask     = (const float*)d_in[1];
    p.polylines = (const float*)d_in[2];
    p.poly_mask = (const float*)d_in[3];
    p.ptype     = (const int*)d_in[4];
    p.tlst      = (const int*)d_in[5];
    p.route     = (const int*)d_in[6];
    p.ae_w0 = (const float*)d_in[7];  p.ae_b0 = (const float*)d_in[8];
    p.ae_w1 = (const float*)d_in[9];  p.ae_b1 = (const float*)d_in[10];
    p.ae_w2 = (const float*)d_in[11]; p.ae_b2 = (const float*)d_in[12];
    p.mp_w0 = (const float*)d_in[13]; p.mp_b0 = (const float*)d_in[14];
    p.mp_w1 = (const float*)d_in[15]; p.mp_b1 = (const float*)d_in[16];
    p.type_emb  = (const float*)d_in[17];
    p.tl_emb    = (const float*)d_in[18];
    p.route_emb = (const float*)d_in[19];
    p.mo_w0 = (const float*)d_in[20]; p.mo_b0 = (const float*)d_in[21];
    p.mo_w1 = (const float*)d_in[22]; p.mo_b1 = (const float*)d_in[23];
    p.mr_w0 = (const float*)d_in[24]; p.mr_b0 = (const float*)d_in[25];
    p.mr_w1 = (const float*)d_in[26]; p.mr_b1 = (const float*)d_in[27];
    p.nr_w0 = (const float*)d_in[28]; p.nr_b0 = (const float*)d_in[29];
    p.nr_w1 = (const float*)d_in[30]; p.nr_b1 = (const float*)d_in[31];
    p.to_w0 = (const float*)d_in[32]; p.to_b0 = (const float*)d_in[33];
    p.to_w1 = (const float*)d_in[34]; p.to_b1 = (const float*)d_in[35];

    p.tau     = (float*)d_out;
    p.map_ctx = (float*)d_out + (size_t)NT*64;
    p.nbr_ctx = p.map_ctx + (size_t)NT*HH;

    float* ws    = (float*)d_ws;
    p.a_emb      = ws;                                   // NT*HH
    p.map_node   = p.a_emb + (size_t)NT*HH;              // B*M*HH
    p.map_nodeT  = p.map_node + (size_t)BB*MM*HH;        // B*HH*MM
    p.map_center = p.map_nodeT + (size_t)BB*MM*HH;       // B*M*2

    k_enc<<<BB*MM + NT/2, 256, 0, stream>>>(p);          // 384 + 1152 = 1536
    k_fat<<<BB*TT*12,     256, 0, stream>>>(p);          // 576
}